// Round 1
// baseline (1768.836 us; speedup 1.0000x reference)
//
#include <hip/hip_runtime.h>

// Problem constants
#define B_  2
#define S_  4096
#define D_  1024
#define H_  8
#define DK_ 128
#define DV_ 128
#define SEG_ 512
#define NSEG_ 8
#define BH_ 16
#define M_ 8192          // B*S

__device__ __forceinline__ float elu1(float x) { return x > 0.f ? x + 1.f : __expf(x); }
__device__ __forceinline__ float sigmoidf(float x) { return 1.f / (1.f + __expf(-x)); }

// ---------------------------------------------------------------------------
// init: mem = 0, z = 1/DK
// ---------------------------------------------------------------------------
__global__ void init_mz(float* __restrict__ Mem, float* __restrict__ Z) {
    int i = blockIdx.x * 256 + threadIdx.x;
    if (i < BH_ * DK_ * DV_) Mem[i] = 0.f;
    if (i < BH_ * DK_)       Z[i]   = 1.f / 128.f;
}

// ---------------------------------------------------------------------------
// QKV projection GEMM: x (8192x1024) @ W[h] (1024x128) for 3 weights x 8 heads
// Tiles: BM=128, BN=128(one head), BK=16. 256 thr, 8x8 microtile.
// Output layout (B,H,S,128).
// ---------------------------------------------------------------------------
__global__ __launch_bounds__(256) void gemm_qkv(
    const float* __restrict__ x, const float* __restrict__ Wk,
    const float* __restrict__ Wv, const float* __restrict__ Wq,
    float* __restrict__ Kb, float* __restrict__ Vb, float* __restrict__ Qb)
{
    __shared__ float As[16][132];
    __shared__ float Bs[16][132];
    const int tid = threadIdx.x, ty = tid >> 4, tx = tid & 15;
    const int m0 = blockIdx.x * 128;
    const int tn = blockIdx.y;            // 0..23
    const int which = tn >> 3, h = tn & 7;
    const float* W = (which == 0 ? Wk : which == 1 ? Wv : Wq) + (size_t)h * D_ * DK_;
    float* dst = (which == 0 ? Kb : which == 1 ? Vb : Qb);
    float acc[8][8] = {};
    for (int k0 = 0; k0 < D_; k0 += 16) {
        #pragma unroll
        for (int it = 0; it < 2; ++it) {          // A: 128 rows x 16 k
            int idx = tid + it * 256;             // 512 float4
            int m = idx >> 2, kc = (idx & 3) << 2;
            float4 a = *(const float4*)(x + (size_t)(m0 + m) * D_ + k0 + kc);
            As[kc + 0][m] = a.x; As[kc + 1][m] = a.y;
            As[kc + 2][m] = a.z; As[kc + 3][m] = a.w;
        }
        #pragma unroll
        for (int it = 0; it < 2; ++it) {          // B: 16 k x 128 n
            int idx = tid + it * 256;
            int kk = idx >> 5, c4 = (idx & 31) << 2;
            *(float4*)&Bs[kk][c4] = *(const float4*)(W + (size_t)(k0 + kk) * DK_ + c4);
        }
        __syncthreads();
        #pragma unroll
        for (int kk = 0; kk < 16; ++kk) {
            float a[8], bb[8];
            *(float4*)a       = *(float4*)&As[kk][ty * 8];
            *(float4*)(a + 4) = *(float4*)&As[kk][ty * 8 + 4];
            *(float4*)bb       = *(float4*)&Bs[kk][tx * 8];
            *(float4*)(bb + 4) = *(float4*)&Bs[kk][tx * 8 + 4];
            #pragma unroll
            for (int i = 0; i < 8; ++i)
                #pragma unroll
                for (int j = 0; j < 8; ++j) acc[i][j] += a[i] * bb[j];
        }
        __syncthreads();
    }
    #pragma unroll
    for (int i = 0; i < 8; ++i) {
        int m = m0 + ty * 8 + i;
        int bb = m >> 12, s = m & 4095;
        float* row = dst + (((size_t)(bb * H_ + h) * S_) + s) * 128 + tx * 8;
        float4 r0 = {acc[i][0], acc[i][1], acc[i][2], acc[i][3]};
        float4 r1 = {acc[i][4], acc[i][5], acc[i][6], acc[i][7]};
        *(float4*)row = r0; *(float4*)(row + 4) = r1;
    }
}

// ---------------------------------------------------------------------------
// Segment-local causal softmax attention (flash-style, online softmax).
// grid.x = bh*8+seg (128), grid.y = qt (8). Writes (1-gate)*att_dot into Att.
// ---------------------------------------------------------------------------
__global__ __launch_bounds__(256) void attn_dot(
    const float* __restrict__ Kb, const float* __restrict__ Vb,
    const float* __restrict__ Qb, const float* __restrict__ betas,
    float* __restrict__ Att)
{
    __shared__ float Qs[64][132];
    __shared__ float KVs[32][132];
    __shared__ float Ps[64][36];
    const int tid = threadIdx.x, ty = tid >> 4, tx = tid & 15;
    const int bh = blockIdx.x >> 3, seg = blockIdx.x & 7;
    const int qt = blockIdx.y;
    const int b = bh >> 3, h = bh & 7;
    const size_t segbase = ((size_t)bh * S_ + seg * SEG_) * 128;
    const float* Qp = Qb + segbase + (size_t)qt * 64 * 128;
    const float* Kp = Kb + segbase;
    const float* Vp = Vb + segbase;
    #pragma unroll
    for (int it = 0; it < 8; ++it) {              // Q tile 64x128
        int idx = tid + it * 256;
        int r = idx >> 5, c4 = (idx & 31) << 2;
        *(float4*)&Qs[r][c4] = *(const float4*)(Qp + r * 128 + c4);
    }
    float o[4][8] = {};
    float mrow[4], lrow[4];
    #pragma unroll
    for (int i = 0; i < 4; ++i) { mrow[i] = -3e38f; lrow[i] = 0.f; }
    const float scale = 0.08838834764831845f;     // 1/sqrt(128)
    const int ntiles = 2 * qt + 2;
    __syncthreads();
    for (int jt = 0; jt < ntiles; ++jt) {
        #pragma unroll
        for (int it = 0; it < 4; ++it) {          // K tile 32x128
            int idx = tid + it * 256;
            int r = idx >> 5, c4 = (idx & 31) << 2;
            *(float4*)&KVs[r][c4] = *(const float4*)(Kp + (jt * 32 + r) * 128 + c4);
        }
        __syncthreads();
        float sc[4][2] = {};
        #pragma unroll 8
        for (int k = 0; k < 128; k += 4) {
            float4 a0 = *(float4*)&Qs[ty * 4 + 0][k];
            float4 a1 = *(float4*)&Qs[ty * 4 + 1][k];
            float4 a2 = *(float4*)&Qs[ty * 4 + 2][k];
            float4 a3 = *(float4*)&Qs[ty * 4 + 3][k];
            float4 b0 = *(float4*)&KVs[tx * 2 + 0][k];
            float4 b1 = *(float4*)&KVs[tx * 2 + 1][k];
            sc[0][0] += a0.x*b0.x + a0.y*b0.y + a0.z*b0.z + a0.w*b0.w;
            sc[0][1] += a0.x*b1.x + a0.y*b1.y + a0.z*b1.z + a0.w*b1.w;
            sc[1][0] += a1.x*b0.x + a1.y*b0.y + a1.z*b0.z + a1.w*b0.w;
            sc[1][1] += a1.x*b1.x + a1.y*b1.y + a1.z*b1.z + a1.w*b1.w;
            sc[2][0] += a2.x*b0.x + a2.y*b0.y + a2.z*b0.z + a2.w*b0.w;
            sc[2][1] += a2.x*b1.x + a2.y*b1.y + a2.z*b1.z + a2.w*b1.w;
            sc[3][0] += a3.x*b0.x + a3.y*b0.y + a3.z*b0.z + a3.w*b0.w;
            sc[3][1] += a3.x*b1.x + a3.y*b1.y + a3.z*b1.z + a3.w*b1.w;
        }
        // mask + scale + online softmax (row groups = 16 lanes, same wave)
        #pragma unroll
        for (int i = 0; i < 4; ++i) {
            int ig = qt * 64 + ty * 4 + i;
            int jg0 = jt * 32 + tx * 2;
            sc[i][0] = (jg0     <= ig) ? sc[i][0] * scale : -3e38f;
            sc[i][1] = (jg0 + 1 <= ig) ? sc[i][1] * scale : -3e38f;
            float rm = fmaxf(sc[i][0], sc[i][1]);
            rm = fmaxf(rm, __shfl_xor(rm, 1));
            rm = fmaxf(rm, __shfl_xor(rm, 2));
            rm = fmaxf(rm, __shfl_xor(rm, 4));
            rm = fmaxf(rm, __shfl_xor(rm, 8));
            float mn = fmaxf(mrow[i], rm);
            float alpha = __expf(mrow[i] - mn);
            mrow[i] = mn;
            float p0 = __expf(sc[i][0] - mn);
            float p1 = __expf(sc[i][1] - mn);
            float rs = p0 + p1;
            rs += __shfl_xor(rs, 1);
            rs += __shfl_xor(rs, 2);
            rs += __shfl_xor(rs, 4);
            rs += __shfl_xor(rs, 8);
            lrow[i] = lrow[i] * alpha + rs;
            Ps[ty * 4 + i][tx * 2 + 0] = p0;
            Ps[ty * 4 + i][tx * 2 + 1] = p1;
            #pragma unroll
            for (int c = 0; c < 8; ++c) o[i][c] *= alpha;
        }
        __syncthreads();                          // done reading K, Ps visible
        #pragma unroll
        for (int it = 0; it < 4; ++it) {          // V tile overwrites KVs
            int idx = tid + it * 256;
            int r = idx >> 5, c4 = (idx & 31) << 2;
            *(float4*)&KVs[r][c4] = *(const float4*)(Vp + (jt * 32 + r) * 128 + c4);
        }
        __syncthreads();
        #pragma unroll
        for (int kb = 0; kb < 32; kb += 4) {      // O += P @ V
            float4 p4[4];
            #pragma unroll
            for (int i = 0; i < 4; ++i) p4[i] = *(float4*)&Ps[ty * 4 + i][kb];
            #pragma unroll
            for (int kk = 0; kk < 4; ++kk) {
                float4 v0 = *(float4*)&KVs[kb + kk][tx * 8];
                float4 v1 = *(float4*)&KVs[kb + kk][tx * 8 + 4];
                #pragma unroll
                for (int i = 0; i < 4; ++i) {
                    float p = (kk == 0) ? p4[i].x : (kk == 1) ? p4[i].y : (kk == 2) ? p4[i].z : p4[i].w;
                    o[i][0] += p * v0.x; o[i][1] += p * v0.y;
                    o[i][2] += p * v0.z; o[i][3] += p * v0.w;
                    o[i][4] += p * v1.x; o[i][5] += p * v1.y;
                    o[i][6] += p * v1.z; o[i][7] += p * v1.w;
                }
            }
        }
        __syncthreads();                          // protect KVs for next jt
    }
    float g[8];
    #pragma unroll
    for (int c = 0; c < 8; ++c) g[c] = 1.f - sigmoidf(betas[h * 128 + tx * 8 + c]);
    #pragma unroll
    for (int i = 0; i < 4; ++i) {
        float inv = 1.f / lrow[i];
        int rl = qt * 64 + ty * 4 + i;
        size_t addr = ((size_t)b * S_ + seg * SEG_ + rl) * (H_ * DV_) + h * 128 + tx * 8;
        float4 r0 = {g[0]*o[i][0]*inv, g[1]*o[i][1]*inv, g[2]*o[i][2]*inv, g[3]*o[i][3]*inv};
        float4 r1 = {g[4]*o[i][4]*inv, g[5]*o[i][5]*inv, g[6]*o[i][6]*inv, g[7]*o[i][7]*inv};
        *(float4*)&Att[addr] = r0; *(float4*)&Att[addr + 4] = r1;
    }
}

// ---------------------------------------------------------------------------
// Per-segment: att_mem = (sigma_q @ mem)/(sigma_q @ z); Att += gate*att_mem
// grid.x = bh*8 + rowtile (128 blocks)
// ---------------------------------------------------------------------------
__global__ __launch_bounds__(256) void seg_attmix(
    const float* __restrict__ Qb, const float* __restrict__ betas,
    const float* __restrict__ Mem, const float* __restrict__ Z,
    float* __restrict__ Att, int seg)
{
    __shared__ float SQs[64][132];
    __shared__ float Zs[128];
    const int tid = threadIdx.x, ty = tid >> 4, tx = tid & 15;
    const int bh = blockIdx.x >> 3, tile = blockIdx.x & 7;
    const int b = bh >> 3, h = bh & 7;
    const float* Qp = Qb + ((size_t)bh * S_ + seg * SEG_ + tile * 64) * 128;
    #pragma unroll
    for (int it = 0; it < 8; ++it) {
        int idx = tid + it * 256;
        int r = idx >> 5, c4 = (idx & 31) << 2;
        float4 q = *(const float4*)(Qp + r * 128 + c4);
        q.x = elu1(q.x); q.y = elu1(q.y); q.z = elu1(q.z); q.w = elu1(q.w);
        *(float4*)&SQs[r][c4] = q;
    }
    if (tid < 128) Zs[tid] = Z[bh * 128 + tid];
    __syncthreads();
    const float* Mp = Mem + (size_t)bh * DK_ * DV_;
    float nq[4][8] = {};
    float dq[4] = {};
    #pragma unroll 4
    for (int k = 0; k < 128; ++k) {
        float a[4];
        #pragma unroll
        for (int i = 0; i < 4; ++i) a[i] = SQs[ty * 4 + i][k];
        float zk = Zs[k];
        float4 m0 = *(const float4*)(Mp + k * 128 + tx * 8);
        float4 m1 = *(const float4*)(Mp + k * 128 + tx * 8 + 4);
        #pragma unroll
        for (int i = 0; i < 4; ++i) {
            dq[i] += a[i] * zk;
            nq[i][0] += a[i] * m0.x; nq[i][1] += a[i] * m0.y;
            nq[i][2] += a[i] * m0.z; nq[i][3] += a[i] * m0.w;
            nq[i][4] += a[i] * m1.x; nq[i][5] += a[i] * m1.y;
            nq[i][6] += a[i] * m1.z; nq[i][7] += a[i] * m1.w;
        }
    }
    float g[8];
    const int col0 = h * 128 + tx * 8;
    #pragma unroll
    for (int c = 0; c < 8; ++c) g[c] = sigmoidf(betas[col0 + c]);
    #pragma unroll
    for (int i = 0; i < 4; ++i) {
        int rl = tile * 64 + ty * 4 + i;
        float inv = 1.f / dq[i];
        size_t addr = ((size_t)b * S_ + seg * SEG_ + rl) * (H_ * DV_) + col0;
        float4 o0 = *(float4*)&Att[addr];
        float4 o1 = *(float4*)&Att[addr + 4];
        o0.x += g[0] * nq[i][0] * inv; o0.y += g[1] * nq[i][1] * inv;
        o0.z += g[2] * nq[i][2] * inv; o0.w += g[3] * nq[i][3] * inv;
        o1.x += g[4] * nq[i][4] * inv; o1.y += g[5] * nq[i][5] * inv;
        o1.z += g[6] * nq[i][6] * inv; o1.w += g[7] * nq[i][7] * inv;
        *(float4*)&Att[addr] = o0; *(float4*)&Att[addr + 4] = o1;
    }
}

// ---------------------------------------------------------------------------
// Per-segment: delta = v - (sigma_k @ mem)/(sigma_k @ z)
// ---------------------------------------------------------------------------
__global__ __launch_bounds__(256) void seg_delta(
    const float* __restrict__ Kb, const float* __restrict__ Vb,
    const float* __restrict__ Mem, const float* __restrict__ Z,
    float* __restrict__ Delta, int seg)
{
    __shared__ float SKs[64][132];
    __shared__ float Zs[128];
    const int tid = threadIdx.x, ty = tid >> 4, tx = tid & 15;
    const int bh = blockIdx.x >> 3, tile = blockIdx.x & 7;
    const float* Kp = Kb + ((size_t)bh * S_ + seg * SEG_ + tile * 64) * 128;
    #pragma unroll
    for (int it = 0; it < 8; ++it) {
        int idx = tid + it * 256;
        int r = idx >> 5, c4 = (idx & 31) << 2;
        float4 kv = *(const float4*)(Kp + r * 128 + c4);
        kv.x = elu1(kv.x); kv.y = elu1(kv.y); kv.z = elu1(kv.z); kv.w = elu1(kv.w);
        *(float4*)&SKs[r][c4] = kv;
    }
    if (tid < 128) Zs[tid] = Z[bh * 128 + tid];
    __syncthreads();
    const float* Mp = Mem + (size_t)bh * DK_ * DV_;
    float nk[4][8] = {};
    float dk[4] = {};
    #pragma unroll 4
    for (int k = 0; k < 128; ++k) {
        float a[4];
        #pragma unroll
        for (int i = 0; i < 4; ++i) a[i] = SKs[ty * 4 + i][k];
        float zk = Zs[k];
        float4 m0 = *(const float4*)(Mp + k * 128 + tx * 8);
        float4 m1 = *(const float4*)(Mp + k * 128 + tx * 8 + 4);
        #pragma unroll
        for (int i = 0; i < 4; ++i) {
            dk[i] += a[i] * zk;
            nk[i][0] += a[i] * m0.x; nk[i][1] += a[i] * m0.y;
            nk[i][2] += a[i] * m0.z; nk[i][3] += a[i] * m0.w;
            nk[i][4] += a[i] * m1.x; nk[i][5] += a[i] * m1.y;
            nk[i][6] += a[i] * m1.z; nk[i][7] += a[i] * m1.w;
        }
    }
    const float* Vp = Vb + ((size_t)bh * S_ + seg * SEG_ + tile * 64) * 128;
    #pragma unroll
    for (int i = 0; i < 4; ++i) {
        int rl = ty * 4 + i;
        float inv = 1.f / dk[i];
        float4 v0 = *(const float4*)(Vp + rl * 128 + tx * 8);
        float4 v1 = *(const float4*)(Vp + rl * 128 + tx * 8 + 4);
        v0.x -= nk[i][0] * inv; v0.y -= nk[i][1] * inv;
        v0.z -= nk[i][2] * inv; v0.w -= nk[i][3] * inv;
        v1.x -= nk[i][4] * inv; v1.y -= nk[i][5] * inv;
        v1.z -= nk[i][6] * inv; v1.w -= nk[i][7] * inv;
        size_t addr = ((size_t)bh * SEG_ + tile * 64 + rl) * 128 + tx * 8;
        *(float4*)&Delta[addr] = v0; *(float4*)&Delta[addr + 4] = v1;
    }
}

// ---------------------------------------------------------------------------
// mem += sigma_k^T @ delta (split-K over S via atomics); z += colsum(sigma_k)
// grid (16 bh, 4 s-chunks)
// ---------------------------------------------------------------------------
__global__ __launch_bounds__(256) void mem_update(
    const float* __restrict__ Kb, const float* __restrict__ Delta,
    float* __restrict__ Mem, float* __restrict__ Z, int seg)
{
    __shared__ float SKs[32][132];
    __shared__ float Ds[32][132];
    const int tid = threadIdx.x, ty = tid >> 4, tx = tid & 15;
    const int bh = blockIdx.x, chunk = blockIdx.y;
    const float* Kp = Kb + ((size_t)bh * S_ + seg * SEG_) * 128;
    const float* Dp = Delta + (size_t)bh * SEG_ * 128;
    float acc[8][8] = {};
    float zp = 0.f;
    for (int s0 = chunk * 128; s0 < chunk * 128 + 128; s0 += 32) {
        #pragma unroll
        for (int it = 0; it < 4; ++it) {
            int idx = tid + it * 256;
            int r = idx >> 5, c4 = (idx & 31) << 2;
            float4 kv = *(const float4*)(Kp + (size_t)(s0 + r) * 128 + c4);
            kv.x = elu1(kv.x); kv.y = elu1(kv.y); kv.z = elu1(kv.z); kv.w = elu1(kv.w);
            *(float4*)&SKs[r][c4] = kv;
            *(float4*)&Ds[r][c4] = *(const float4*)(Dp + (size_t)(s0 + r) * 128 + c4);
        }
        __syncthreads();
        if (tid < 128) {
            #pragma unroll
            for (int s = 0; s < 32; ++s) zp += SKs[s][tid];
        }
        #pragma unroll
        for (int s = 0; s < 32; ++s) {
            float a[8], bb[8];
            *(float4*)a       = *(float4*)&SKs[s][ty * 8];
            *(float4*)(a + 4) = *(float4*)&SKs[s][ty * 8 + 4];
            *(float4*)bb       = *(float4*)&Ds[s][tx * 8];
            *(float4*)(bb + 4) = *(float4*)&Ds[s][tx * 8 + 4];
            #pragma unroll
            for (int i = 0; i < 8; ++i)
                #pragma unroll
                for (int j = 0; j < 8; ++j) acc[i][j] += a[i] * bb[j];
        }
        __syncthreads();
    }
    float* Mp = Mem + (size_t)bh * DK_ * DV_;
    #pragma unroll
    for (int i = 0; i < 8; ++i)
        #pragma unroll
        for (int j = 0; j < 8; ++j)
            atomicAdd(&Mp[(ty * 8 + i) * 128 + tx * 8 + j], acc[i][j]);
    if (tid < 128) atomicAdd(&Z[bh * 128 + tid], zp);
}

// ---------------------------------------------------------------------------
// Output GEMM: Att (8192x1024) @ Wout (1024x1024) -> out
// ---------------------------------------------------------------------------
__global__ __launch_bounds__(256) void gemm_out(
    const float* __restrict__ A, const float* __restrict__ Bw, float* __restrict__ C)
{
    __shared__ float As[16][132];
    __shared__ float Bs[16][132];
    const int tid = threadIdx.x, ty = tid >> 4, tx = tid & 15;
    const int m0 = blockIdx.x * 128, n0 = blockIdx.y * 128;
    float acc[8][8] = {};
    for (int k0 = 0; k0 < 1024; k0 += 16) {
        #pragma unroll
        for (int it = 0; it < 2; ++it) {
            int idx = tid + it * 256;
            int m = idx >> 2, kc = (idx & 3) << 2;
            float4 a = *(const float4*)(A + (size_t)(m0 + m) * 1024 + k0 + kc);
            As[kc + 0][m] = a.x; As[kc + 1][m] = a.y;
            As[kc + 2][m] = a.z; As[kc + 3][m] = a.w;
        }
        #pragma unroll
        for (int it = 0; it < 2; ++it) {
            int idx = tid + it * 256;
            int kk = idx >> 5, c4 = (idx & 31) << 2;
            *(float4*)&Bs[kk][c4] = *(const float4*)(Bw + (size_t)(k0 + kk) * 1024 + n0 + c4);
        }
        __syncthreads();
        #pragma unroll
        for (int kk = 0; kk < 16; ++kk) {
            float a[8], bb[8];
            *(float4*)a       = *(float4*)&As[kk][ty * 8];
            *(float4*)(a + 4) = *(float4*)&As[kk][ty * 8 + 4];
            *(float4*)bb       = *(float4*)&Bs[kk][tx * 8];
            *(float4*)(bb + 4) = *(float4*)&Bs[kk][tx * 8 + 4];
            #pragma unroll
            for (int i = 0; i < 8; ++i)
                #pragma unroll
                for (int j = 0; j < 8; ++j) acc[i][j] += a[i] * bb[j];
        }
        __syncthreads();
    }
    #pragma unroll
    for (int i = 0; i < 8; ++i) {
        float* row = C + (size_t)(m0 + ty * 8 + i) * 1024 + n0 + tx * 8;
        float4 r0 = {acc[i][0], acc[i][1], acc[i][2], acc[i][3]};
        float4 r1 = {acc[i][4], acc[i][5], acc[i][6], acc[i][7]};
        *(float4*)row = r0; *(float4*)(row + 4) = r1;
    }
}

extern "C" void kernel_launch(void* const* d_in, const int* in_sizes, int n_in,
                              void* d_out, int out_size, void* d_ws, size_t ws_size,
                              hipStream_t stream) {
    const float* x     = (const float*)d_in[0];
    const float* Wk    = (const float*)d_in[1];
    const float* Wv    = (const float*)d_in[2];
    const float* Wq    = (const float*)d_in[3];
    const float* Wout  = (const float*)d_in[4];
    const float* betas = (const float*)d_in[5];
    float* out = (float*)d_out;
    float* ws = (float*)d_ws;
    // workspace layout (floats)
    float* Kb    = ws;                       // 8388608  (B,H,S,128)
    float* Vb    = Kb + 8388608;             // 8388608
    float* Qb    = Vb + 8388608;             // 8388608
    float* Att   = Qb + 8388608;             // 8388608  (B,S,H*DV)
    float* Delta = Att + 8388608;            // 1048576  (BH,SEG,DV)
    float* Mem   = Delta + 1048576;          // 262144   (BH,DK,DV)
    float* Z     = Mem + 262144;             // 2048     (BH,DK)

    init_mz<<<1024, 256, 0, stream>>>(Mem, Z);
    gemm_qkv<<<dim3(64, 24), 256, 0, stream>>>(x, Wk, Wv, Wq, Kb, Vb, Qb);
    attn_dot<<<dim3(128, 8), 256, 0, stream>>>(Kb, Vb, Qb, betas, Att);
    for (int seg = 0; seg < NSEG_; ++seg) {
        seg_attmix<<<128, 256, 0, stream>>>(Qb, betas, Mem, Z, Att, seg);
        seg_delta<<<128, 256, 0, stream>>>(Kb, Vb, Mem, Z, Delta, seg);
        mem_update<<<dim3(16, 4), 256, 0, stream>>>(Kb, Delta, Mem, Z, seg);
    }
    gemm_out<<<dim3(64, 8), 256, 0, stream>>>(Att, Wout, out);
}

// Round 2
// 1134.495 us; speedup vs baseline: 1.5591x; 1.5591x over previous
//
#include <hip/hip_runtime.h>

// Problem constants
#define B_  2
#define S_  4096
#define D_  1024
#define H_  8
#define DK_ 128
#define DV_ 128
#define SEG_ 512
#define NSEG_ 8
#define BH_ 16
#define M_ 8192          // B*S

typedef __attribute__((ext_vector_type(8))) short bf16x8;
typedef __attribute__((ext_vector_type(4))) float f32x4;

__device__ __forceinline__ float elu1(float x) { return x > 0.f ? x + 1.f : __expf(x); }
__device__ __forceinline__ float sigmoidf(float x) { return 1.f / (1.f + __expf(-x)); }

__device__ __forceinline__ unsigned short f2b(float f) {  // RNE fp32->bf16
    union { float f; unsigned int u; } x; x.f = f;
    unsigned int r = x.u + 0x7fffu + ((x.u >> 16) & 1u);
    return (unsigned short)(r >> 16);
}

__device__ __forceinline__ void gl2lds16(const void* g, void* l) {
    __builtin_amdgcn_global_load_lds(
        (const __attribute__((address_space(1))) void*)g,
        (__attribute__((address_space(3))) void*)l, 16, 0, 0);
}

// ---------------------------------------------------------------------------
// init: mem = 0, z = 1/DK
// ---------------------------------------------------------------------------
__global__ void init_mz(float* __restrict__ Mem, float* __restrict__ Z) {
    int i = blockIdx.x * 256 + threadIdx.x;
    if (i < BH_ * DK_ * DV_) Mem[i] = 0.f;
    if (i < BH_ * DK_)       Z[i]   = 1.f / 128.f;
}

// ---------------------------------------------------------------------------
// fp32 -> bf16 row-major convert (n divisible by 1024)
// ---------------------------------------------------------------------------
__global__ __launch_bounds__(256) void conv_bf16(
    const float* __restrict__ src, unsigned short* __restrict__ dst)
{
    int i = (blockIdx.x * 256 + threadIdx.x) * 4;
    float4 v = *(const float4*)(src + i);
    ushort4 o;
    o.x = f2b(v.x); o.y = f2b(v.y); o.z = f2b(v.z); o.w = f2b(v.w);
    *(ushort4*)(dst + i) = o;
}

// ---------------------------------------------------------------------------
// fp32 (R x C) -> bf16 transposed (C x R). blockIdx.z = matrix index.
// ---------------------------------------------------------------------------
__global__ __launch_bounds__(256) void transpose_conv(
    const float* __restrict__ src, unsigned short* __restrict__ dst, int R, int C)
{
    __shared__ float tile[32][33];
    const size_t moff = (size_t)blockIdx.z * R * C;
    src += moff; dst += moff;
    const int c0 = blockIdx.x * 32, r0 = blockIdx.y * 32;
    const int tx = threadIdx.x & 31, ty = threadIdx.x >> 5;   // 32 x 8
    #pragma unroll
    for (int i = 0; i < 32; i += 8)
        tile[ty + i][tx] = src[(size_t)(r0 + ty + i) * C + c0 + tx];
    __syncthreads();
    #pragma unroll
    for (int i = 0; i < 32; i += 8)
        dst[(size_t)(c0 + ty + i) * R + r0 + tx] = f2b(tile[tx][ty + i]);
}

// ---------------------------------------------------------------------------
// bf16 MFMA GEMM core: 128x128 tile, BK=32, 16x16x32 MFMA, 4x4 acc per wave.
// A: row-major (128 x K) at tile base, ld = lda. Bt: row-major (128 x K) = B^T.
// LDS layout [row][k], 32 k per stage, unpadded (global_load_lds order).
// ---------------------------------------------------------------------------
__device__ __forceinline__ void mfma_gemm_128(
    const unsigned short* __restrict__ A, int lda,
    const unsigned short* __restrict__ Bt, int ldb, int K,
    unsigned short* As, unsigned short* Bs, f32x4 acc[4][4])
{
    const int tid = threadIdx.x;
    const int wave = tid >> 6, lane = tid & 63;
    const int r4 = lane >> 2, c4 = (lane & 3) * 8;     // staging: row in 16-group, k-part
    const int lrow = lane & 15, lquad = lane >> 4;
    const int wm = (wave >> 1) * 64, wn = (wave & 1) * 64;
    for (int k0 = 0; k0 < K; k0 += 32) {
        #pragma unroll
        for (int i = 0; i < 2; ++i) {
            int ar = wave * 32 + i * 16;               // wave-uniform LDS base row
            gl2lds16(A  + (size_t)(ar + r4) * lda + k0 + c4, As + ar * 32);
            gl2lds16(Bt + (size_t)(ar + r4) * ldb + k0 + c4, Bs + ar * 32);
        }
        __syncthreads();
        bf16x8 af[4], bfr[4];
        #pragma unroll
        for (int i = 0; i < 4; ++i)
            af[i] = *(const bf16x8*)(As + (wm + i * 16 + lrow) * 32 + lquad * 8);
        #pragma unroll
        for (int j = 0; j < 4; ++j)
            bfr[j] = *(const bf16x8*)(Bs + (wn + j * 16 + lrow) * 32 + lquad * 8);
        #pragma unroll
        for (int i = 0; i < 4; ++i)
            #pragma unroll
            for (int j = 0; j < 4; ++j)
                acc[i][j] = __builtin_amdgcn_mfma_f32_16x16x32_bf16(af[i], bfr[j], acc[i][j], 0, 0, 0);
        __syncthreads();
    }
}

// ---------------------------------------------------------------------------
// QKV projection: xb (8192x1024 bf16) @ Wtb[panel] (128x1024 bf16 = W^T)
// panel = which*8 + h. Output fp32 (B,H,S,128).
// ---------------------------------------------------------------------------
__global__ __launch_bounds__(256) void gemm_qkv_mfma(
    const unsigned short* __restrict__ xb, const unsigned short* __restrict__ Wtb,
    float* __restrict__ Kb, float* __restrict__ Vb, float* __restrict__ Qb)
{
    __shared__ unsigned short As[128 * 32];
    __shared__ unsigned short Bs[128 * 32];
    const int m0 = blockIdx.x * 128;
    const int panel = blockIdx.y;
    const int which = panel >> 3, h = panel & 7;
    float* dst = which == 0 ? Kb : which == 1 ? Vb : Qb;
    f32x4 acc[4][4] = {};
    mfma_gemm_128(xb + (size_t)m0 * 1024, 1024,
                  Wtb + (size_t)panel * 128 * 1024, 1024, 1024, As, Bs, acc);
    const int tid = threadIdx.x, wave = tid >> 6, lane = tid & 63;
    const int lrow = lane & 15, lquad = lane >> 4;
    const int wm = (wave >> 1) * 64, wn = (wave & 1) * 64;
    #pragma unroll
    for (int i = 0; i < 4; ++i)
        #pragma unroll
        for (int r = 0; r < 4; ++r) {
            int m = m0 + wm + i * 16 + lquad * 4 + r;
            int b = m >> 12, s = m & 4095;
            float* row = dst + (((size_t)(b * 8 + h) * 4096) + s) * 128;
            #pragma unroll
            for (int j = 0; j < 4; ++j)
                row[wn + j * 16 + lrow] = acc[i][j][r];
        }
}

// ---------------------------------------------------------------------------
// Output projection: Attb (8192x1024 bf16) @ Woutb (1024x1024 bf16 = Wout^T)
// ---------------------------------------------------------------------------
__global__ __launch_bounds__(256) void gemm_out_mfma(
    const unsigned short* __restrict__ A, const unsigned short* __restrict__ Bt,
    float* __restrict__ C)
{
    __shared__ unsigned short As[128 * 32];
    __shared__ unsigned short Bs[128 * 32];
    const int m0 = blockIdx.x * 128, n0 = blockIdx.y * 128;
    f32x4 acc[4][4] = {};
    mfma_gemm_128(A + (size_t)m0 * 1024, 1024,
                  Bt + (size_t)n0 * 1024, 1024, 1024, As, Bs, acc);
    const int tid = threadIdx.x, wave = tid >> 6, lane = tid & 63;
    const int lrow = lane & 15, lquad = lane >> 4;
    const int wm = (wave >> 1) * 64, wn = (wave & 1) * 64;
    #pragma unroll
    for (int i = 0; i < 4; ++i)
        #pragma unroll
        for (int r = 0; r < 4; ++r) {
            int m = m0 + wm + i * 16 + lquad * 4 + r;
            #pragma unroll
            for (int j = 0; j < 4; ++j)
                C[(size_t)m * 1024 + n0 + wn + j * 16 + lrow] = acc[i][j][r];
        }
}

// ---------------------------------------------------------------------------
// Segment-local causal softmax attention (flash-style, online softmax).
// grid.x = bh*8+seg (128), grid.y = qt (8). Writes (1-gate)*att_dot into Att.
// ---------------------------------------------------------------------------
__global__ __launch_bounds__(256) void attn_dot(
    const float* __restrict__ Kb, const float* __restrict__ Vb,
    const float* __restrict__ Qb, const float* __restrict__ betas,
    float* __restrict__ Att)
{
    __shared__ float Qs[64][132];
    __shared__ float KVs[32][132];
    __shared__ float Ps[64][36];
    const int tid = threadIdx.x, ty = tid >> 4, tx = tid & 15;
    const int bh = blockIdx.x >> 3, seg = blockIdx.x & 7;
    const int qt = blockIdx.y;
    const int b = bh >> 3, h = bh & 7;
    const size_t segbase = ((size_t)bh * S_ + seg * SEG_) * 128;
    const float* Qp = Qb + segbase + (size_t)qt * 64 * 128;
    const float* Kp = Kb + segbase;
    const float* Vp = Vb + segbase;
    #pragma unroll
    for (int it = 0; it < 8; ++it) {              // Q tile 64x128
        int idx = tid + it * 256;
        int r = idx >> 5, c4 = (idx & 31) << 2;
        *(float4*)&Qs[r][c4] = *(const float4*)(Qp + r * 128 + c4);
    }
    float o[4][8] = {};
    float mrow[4], lrow[4];
    #pragma unroll
    for (int i = 0; i < 4; ++i) { mrow[i] = -3e38f; lrow[i] = 0.f; }
    const float scale = 0.08838834764831845f;     // 1/sqrt(128)
    const int ntiles = 2 * qt + 2;
    __syncthreads();
    for (int jt = 0; jt < ntiles; ++jt) {
        #pragma unroll
        for (int it = 0; it < 4; ++it) {          // K tile 32x128
            int idx = tid + it * 256;
            int r = idx >> 5, c4 = (idx & 31) << 2;
            *(float4*)&KVs[r][c4] = *(const float4*)(Kp + (jt * 32 + r) * 128 + c4);
        }
        __syncthreads();
        float sc[4][2] = {};
        #pragma unroll 8
        for (int k = 0; k < 128; k += 4) {
            float4 a0 = *(float4*)&Qs[ty * 4 + 0][k];
            float4 a1 = *(float4*)&Qs[ty * 4 + 1][k];
            float4 a2 = *(float4*)&Qs[ty * 4 + 2][k];
            float4 a3 = *(float4*)&Qs[ty * 4 + 3][k];
            float4 b0 = *(float4*)&KVs[tx * 2 + 0][k];
            float4 b1 = *(float4*)&KVs[tx * 2 + 1][k];
            sc[0][0] += a0.x*b0.x + a0.y*b0.y + a0.z*b0.z + a0.w*b0.w;
            sc[0][1] += a0.x*b1.x + a0.y*b1.y + a0.z*b1.z + a0.w*b1.w;
            sc[1][0] += a1.x*b0.x + a1.y*b0.y + a1.z*b0.z + a1.w*b0.w;
            sc[1][1] += a1.x*b1.x + a1.y*b1.y + a1.z*b1.z + a1.w*b1.w;
            sc[2][0] += a2.x*b0.x + a2.y*b0.y + a2.z*b0.z + a2.w*b0.w;
            sc[2][1] += a2.x*b1.x + a2.y*b1.y + a2.z*b1.z + a2.w*b1.w;
            sc[3][0] += a3.x*b0.x + a3.y*b0.y + a3.z*b0.z + a3.w*b0.w;
            sc[3][1] += a3.x*b1.x + a3.y*b1.y + a3.z*b1.z + a3.w*b1.w;
        }
        #pragma unroll
        for (int i = 0; i < 4; ++i) {
            int ig = qt * 64 + ty * 4 + i;
            int jg0 = jt * 32 + tx * 2;
            sc[i][0] = (jg0     <= ig) ? sc[i][0] * scale : -3e38f;
            sc[i][1] = (jg0 + 1 <= ig) ? sc[i][1] * scale : -3e38f;
            float rm = fmaxf(sc[i][0], sc[i][1]);
            rm = fmaxf(rm, __shfl_xor(rm, 1));
            rm = fmaxf(rm, __shfl_xor(rm, 2));
            rm = fmaxf(rm, __shfl_xor(rm, 4));
            rm = fmaxf(rm, __shfl_xor(rm, 8));
            float mn = fmaxf(mrow[i], rm);
            float alpha = __expf(mrow[i] - mn);
            mrow[i] = mn;
            float p0 = __expf(sc[i][0] - mn);
            float p1 = __expf(sc[i][1] - mn);
            float rs = p0 + p1;
            rs += __shfl_xor(rs, 1);
            rs += __shfl_xor(rs, 2);
            rs += __shfl_xor(rs, 4);
            rs += __shfl_xor(rs, 8);
            lrow[i] = lrow[i] * alpha + rs;
            Ps[ty * 4 + i][tx * 2 + 0] = p0;
            Ps[ty * 4 + i][tx * 2 + 1] = p1;
            #pragma unroll
            for (int c = 0; c < 8; ++c) o[i][c] *= alpha;
        }
        __syncthreads();
        #pragma unroll
        for (int it = 0; it < 4; ++it) {          // V tile overwrites KVs
            int idx = tid + it * 256;
            int r = idx >> 5, c4 = (idx & 31) << 2;
            *(float4*)&KVs[r][c4] = *(const float4*)(Vp + (jt * 32 + r) * 128 + c4);
        }
        __syncthreads();
        #pragma unroll
        for (int kb = 0; kb < 32; kb += 4) {      // O += P @ V
            float4 p4[4];
            #pragma unroll
            for (int i = 0; i < 4; ++i) p4[i] = *(float4*)&Ps[ty * 4 + i][kb];
            #pragma unroll
            for (int kk = 0; kk < 4; ++kk) {
                float4 v0 = *(float4*)&KVs[kb + kk][tx * 8];
                float4 v1 = *(float4*)&KVs[kb + kk][tx * 8 + 4];
                #pragma unroll
                for (int i = 0; i < 4; ++i) {
                    float p = (kk == 0) ? p4[i].x : (kk == 1) ? p4[i].y : (kk == 2) ? p4[i].z : p4[i].w;
                    o[i][0] += p * v0.x; o[i][1] += p * v0.y;
                    o[i][2] += p * v0.z; o[i][3] += p * v0.w;
                    o[i][4] += p * v1.x; o[i][5] += p * v1.y;
                    o[i][6] += p * v1.z; o[i][7] += p * v1.w;
                }
            }
        }
        __syncthreads();
    }
    float g[8];
    #pragma unroll
    for (int c = 0; c < 8; ++c) g[c] = 1.f - sigmoidf(betas[h * 128 + tx * 8 + c]);
    #pragma unroll
    for (int i = 0; i < 4; ++i) {
        float inv = 1.f / lrow[i];
        int rl = qt * 64 + ty * 4 + i;
        size_t addr = ((size_t)b * S_ + seg * SEG_ + rl) * (H_ * DV_) + h * 128 + tx * 8;
        float4 r0 = {g[0]*o[i][0]*inv, g[1]*o[i][1]*inv, g[2]*o[i][2]*inv, g[3]*o[i][3]*inv};
        float4 r1 = {g[4]*o[i][4]*inv, g[5]*o[i][5]*inv, g[6]*o[i][6]*inv, g[7]*o[i][7]*inv};
        *(float4*)&Att[addr] = r0; *(float4*)&Att[addr + 4] = r1;
    }
}

// ---------------------------------------------------------------------------
// Per-segment: att_mem = (sigma_q @ mem)/(sigma_q @ z); Att += gate*att_mem
// ---------------------------------------------------------------------------
__global__ __launch_bounds__(256) void seg_attmix(
    const float* __restrict__ Qb, const float* __restrict__ betas,
    const float* __restrict__ Mem, const float* __restrict__ Z,
    float* __restrict__ Att, int seg)
{
    __shared__ float SQs[64][132];
    __shared__ float Zs[128];
    const int tid = threadIdx.x, ty = tid >> 4, tx = tid & 15;
    const int bh = blockIdx.x >> 3, tile = blockIdx.x & 7;
    const int b = bh >> 3, h = bh & 7;
    const float* Qp = Qb + ((size_t)bh * S_ + seg * SEG_ + tile * 64) * 128;
    #pragma unroll
    for (int it = 0; it < 8; ++it) {
        int idx = tid + it * 256;
        int r = idx >> 5, c4 = (idx & 31) << 2;
        float4 q = *(const float4*)(Qp + r * 128 + c4);
        q.x = elu1(q.x); q.y = elu1(q.y); q.z = elu1(q.z); q.w = elu1(q.w);
        *(float4*)&SQs[r][c4] = q;
    }
    if (tid < 128) Zs[tid] = Z[bh * 128 + tid];
    __syncthreads();
    const float* Mp = Mem + (size_t)bh * DK_ * DV_;
    float nq[4][8] = {};
    float dq[4] = {};
    #pragma unroll 4
    for (int k = 0; k < 128; ++k) {
        float a[4];
        #pragma unroll
        for (int i = 0; i < 4; ++i) a[i] = SQs[ty * 4 + i][k];
        float zk = Zs[k];
        float4 m0 = *(const float4*)(Mp + k * 128 + tx * 8);
        float4 m1 = *(const float4*)(Mp + k * 128 + tx * 8 + 4);
        #pragma unroll
        for (int i = 0; i < 4; ++i) {
            dq[i] += a[i] * zk;
            nq[i][0] += a[i] * m0.x; nq[i][1] += a[i] * m0.y;
            nq[i][2] += a[i] * m0.z; nq[i][3] += a[i] * m0.w;
            nq[i][4] += a[i] * m1.x; nq[i][5] += a[i] * m1.y;
            nq[i][6] += a[i] * m1.z; nq[i][7] += a[i] * m1.w;
        }
    }
    float g[8];
    const int col0 = h * 128 + tx * 8;
    #pragma unroll
    for (int c = 0; c < 8; ++c) g[c] = sigmoidf(betas[col0 + c]);
    #pragma unroll
    for (int i = 0; i < 4; ++i) {
        int rl = tile * 64 + ty * 4 + i;
        float inv = 1.f / dq[i];
        size_t addr = ((size_t)b * S_ + seg * SEG_ + rl) * (H_ * DV_) + col0;
        float4 o0 = *(float4*)&Att[addr];
        float4 o1 = *(float4*)&Att[addr + 4];
        o0.x += g[0] * nq[i][0] * inv; o0.y += g[1] * nq[i][1] * inv;
        o0.z += g[2] * nq[i][2] * inv; o0.w += g[3] * nq[i][3] * inv;
        o1.x += g[4] * nq[i][4] * inv; o1.y += g[5] * nq[i][5] * inv;
        o1.z += g[6] * nq[i][6] * inv; o1.w += g[7] * nq[i][7] * inv;
        *(float4*)&Att[addr] = o0; *(float4*)&Att[addr + 4] = o1;
    }
}

// ---------------------------------------------------------------------------
// Per-segment: delta = v - (sigma_k @ mem)/(sigma_k @ z)
// ---------------------------------------------------------------------------
__global__ __launch_bounds__(256) void seg_delta(
    const float* __restrict__ Kb, const float* __restrict__ Vb,
    const float* __restrict__ Mem, const float* __restrict__ Z,
    float* __restrict__ Delta, int seg)
{
    __shared__ float SKs[64][132];
    __shared__ float Zs[128];
    const int tid = threadIdx.x, ty = tid >> 4, tx = tid & 15;
    const int bh = blockIdx.x >> 3, tile = blockIdx.x & 7;
    const float* Kp = Kb + ((size_t)bh * S_ + seg * SEG_ + tile * 64) * 128;
    #pragma unroll
    for (int it = 0; it < 8; ++it) {
        int idx = tid + it * 256;
        int r = idx >> 5, c4 = (idx & 31) << 2;
        float4 kv = *(const float4*)(Kp + r * 128 + c4);
        kv.x = elu1(kv.x); kv.y = elu1(kv.y); kv.z = elu1(kv.z); kv.w = elu1(kv.w);
        *(float4*)&SKs[r][c4] = kv;
    }
    if (tid < 128) Zs[tid] = Z[bh * 128 + tid];
    __syncthreads();
    const float* Mp = Mem + (size_t)bh * DK_ * DV_;
    float nk[4][8] = {};
    float dk[4] = {};
    #pragma unroll 4
    for (int k = 0; k < 128; ++k) {
        float a[4];
        #pragma unroll
        for (int i = 0; i < 4; ++i) a[i] = SKs[ty * 4 + i][k];
        float zk = Zs[k];
        float4 m0 = *(const float4*)(Mp + k * 128 + tx * 8);
        float4 m1 = *(const float4*)(Mp + k * 128 + tx * 8 + 4);
        #pragma unroll
        for (int i = 0; i < 4; ++i) {
            dk[i] += a[i] * zk;
            nk[i][0] += a[i] * m0.x; nk[i][1] += a[i] * m0.y;
            nk[i][2] += a[i] * m0.z; nk[i][3] += a[i] * m0.w;
            nk[i][4] += a[i] * m1.x; nk[i][5] += a[i] * m1.y;
            nk[i][6] += a[i] * m1.z; nk[i][7] += a[i] * m1.w;
        }
    }
    const float* Vp = Vb + ((size_t)bh * S_ + seg * SEG_ + tile * 64) * 128;
    #pragma unroll
    for (int i = 0; i < 4; ++i) {
        int rl = ty * 4 + i;
        float inv = 1.f / dk[i];
        float4 v0 = *(const float4*)(Vp + rl * 128 + tx * 8);
        float4 v1 = *(const float4*)(Vp + rl * 128 + tx * 8 + 4);
        v0.x -= nk[i][0] * inv; v0.y -= nk[i][1] * inv;
        v0.z -= nk[i][2] * inv; v0.w -= nk[i][3] * inv;
        v1.x -= nk[i][4] * inv; v1.y -= nk[i][5] * inv;
        v1.z -= nk[i][6] * inv; v1.w -= nk[i][7] * inv;
        size_t addr = ((size_t)bh * SEG_ + tile * 64 + rl) * 128 + tx * 8;
        *(float4*)&Delta[addr] = v0; *(float4*)&Delta[addr + 4] = v1;
    }
}

// ---------------------------------------------------------------------------
// mem += sigma_k^T @ delta (split-K via atomics); z += colsum(sigma_k)
// ---------------------------------------------------------------------------
__global__ __launch_bounds__(256) void mem_update(
    const float* __restrict__ Kb, const float* __restrict__ Delta,
    float* __restrict__ Mem, float* __restrict__ Z, int seg)
{
    __shared__ float SKs[32][132];
    __shared__ float Ds[32][132];
    const int tid = threadIdx.x, ty = tid >> 4, tx = tid & 15;
    const int bh = blockIdx.x, chunk = blockIdx.y;
    const float* Kp = Kb + ((size_t)bh * S_ + seg * SEG_) * 128;
    const float* Dp = Delta + (size_t)bh * SEG_ * 128;
    float acc[8][8] = {};
    float zp = 0.f;
    for (int s0 = chunk * 128; s0 < chunk * 128 + 128; s0 += 32) {
        #pragma unroll
        for (int it = 0; it < 4; ++it) {
            int idx = tid + it * 256;
            int r = idx >> 5, c4 = (idx & 31) << 2;
            float4 kv = *(const float4*)(Kp + (size_t)(s0 + r) * 128 + c4);
            kv.x = elu1(kv.x); kv.y = elu1(kv.y); kv.z = elu1(kv.z); kv.w = elu1(kv.w);
            *(float4*)&SKs[r][c4] = kv;
            *(float4*)&Ds[r][c4] = *(const float4*)(Dp + (size_t)(s0 + r) * 128 + c4);
        }
        __syncthreads();
        if (tid < 128) {
            #pragma unroll
            for (int s = 0; s < 32; ++s) zp += SKs[s][tid];
        }
        #pragma unroll
        for (int s = 0; s < 32; ++s) {
            float a[8], bb[8];
            *(float4*)a       = *(float4*)&SKs[s][ty * 8];
            *(float4*)(a + 4) = *(float4*)&SKs[s][ty * 8 + 4];
            *(float4*)bb       = *(float4*)&Ds[s][tx * 8];
            *(float4*)(bb + 4) = *(float4*)&Ds[s][tx * 8 + 4];
            #pragma unroll
            for (int i = 0; i < 8; ++i)
                #pragma unroll
                for (int j = 0; j < 8; ++j) acc[i][j] += a[i] * bb[j];
        }
        __syncthreads();
    }
    float* Mp = Mem + (size_t)bh * DK_ * DV_;
    #pragma unroll
    for (int i = 0; i < 8; ++i)
        #pragma unroll
        for (int j = 0; j < 8; ++j)
            atomicAdd(&Mp[(ty * 8 + i) * 128 + tx * 8 + j], acc[i][j]);
    if (tid < 128) atomicAdd(&Z[bh * 128 + tid], zp);
}

extern "C" void kernel_launch(void* const* d_in, const int* in_sizes, int n_in,
                              void* d_out, int out_size, void* d_ws, size_t ws_size,
                              hipStream_t stream) {
    const float* x     = (const float*)d_in[0];
    const float* Wk    = (const float*)d_in[1];
    const float* Wv    = (const float*)d_in[2];
    const float* Wq    = (const float*)d_in[3];
    const float* Wout  = (const float*)d_in[4];
    const float* betas = (const float*)d_in[5];
    float* out = (float*)d_out;
    float* ws = (float*)d_ws;
    // fp32 workspace (same 141 MB footprint as round 1)
    float* Kb    = ws;                       // (B,H,S,128)
    float* Vb    = Kb + 8388608;
    float* Qb    = Vb + 8388608;
    float* Att   = Qb + 8388608;             // (B,S,H*DV)
    float* Delta = Att + 8388608;            // (BH,SEG,DV)
    float* Mem   = Delta + 1048576;          // (BH,DK,DV)
    float* Z     = Mem + 262144;             // (BH,DK)
    // bf16 aliases into dead fp32 regions:
    //  - xb/Wtb live in Att region, consumed by gemm_qkv before attn_dot writes Att
    //  - Attb/Woutb live in Kb/Vb regions, created after the scan is done with K/V
    unsigned short* xb    = (unsigned short*)Att;            // 8388608 us
    unsigned short* Wtb   = (unsigned short*)Att + 8388608;  // 3145728 us (3,8,128,1024)
    unsigned short* Attb  = (unsigned short*)Kb;             // 8388608 us
    unsigned short* Woutb = (unsigned short*)Vb;             // 1048576 us (1024x1024 = Wout^T)

    init_mz<<<1024, 256, 0, stream>>>(Mem, Z);
    conv_bf16<<<8192, 256, 0, stream>>>(x, xb);
    transpose_conv<<<dim3(4, 32, 8), 256, 0, stream>>>(Wk, Wtb,                1024, 128);
    transpose_conv<<<dim3(4, 32, 8), 256, 0, stream>>>(Wv, Wtb +  8 * 131072,  1024, 128);
    transpose_conv<<<dim3(4, 32, 8), 256, 0, stream>>>(Wq, Wtb + 16 * 131072,  1024, 128);
    gemm_qkv_mfma<<<dim3(64, 24), 256, 0, stream>>>(xb, Wtb, Kb, Vb, Qb);
    attn_dot<<<dim3(128, 8), 256, 0, stream>>>(Kb, Vb, Qb, betas, Att);
    for (int seg = 0; seg < NSEG_; ++seg) {
        seg_attmix<<<128, 256, 0, stream>>>(Qb, betas, Mem, Z, Att, seg);
        seg_delta<<<128, 256, 0, stream>>>(Kb, Vb, Mem, Z, Delta, seg);
        mem_update<<<dim3(16, 4), 256, 0, stream>>>(Kb, Delta, Mem, Z, seg);
    }
    conv_bf16<<<8192, 256, 0, stream>>>(Att, Attb);
    transpose_conv<<<dim3(32, 32, 1), 256, 0, stream>>>(Wout, Woutb, 1024, 1024);
    gemm_out_mfma<<<dim3(64, 8), 256, 0, stream>>>(Attb, Woutb, out);
}

// Round 3
// 741.788 us; speedup vs baseline: 2.3846x; 1.5294x over previous
//
#include <hip/hip_runtime.h>

// Problem constants
#define B_  2
#define S_  4096
#define D_  1024
#define H_  8
#define DK_ 128
#define DV_ 128
#define SEG_ 512
#define NSEG_ 8
#define BH_ 16
#define M_ 8192          // B*S

typedef __attribute__((ext_vector_type(8))) short bf16x8;
typedef __attribute__((ext_vector_type(4))) float f32x4;

__device__ __forceinline__ float elu1(float x) { return x > 0.f ? x + 1.f : __expf(x); }
__device__ __forceinline__ float sigmoidf(float x) { return 1.f / (1.f + __expf(-x)); }

__device__ __forceinline__ unsigned short f2b(float f) {  // RNE fp32->bf16
    union { float f; unsigned int u; } x; x.f = f;
    unsigned int r = x.u + 0x7fffu + ((x.u >> 16) & 1u);
    return (unsigned short)(r >> 16);
}
__device__ __forceinline__ float b2f(unsigned short u) {
    union { unsigned int u; float f; } x; x.u = ((unsigned int)u) << 16; return x.f;
}

__device__ __forceinline__ void gl2lds16(const void* g, void* l) {
    __builtin_amdgcn_global_load_lds(
        (const __attribute__((address_space(1))) void*)g,
        (__attribute__((address_space(3))) void*)l, 16, 0, 0);
}

// ---------------------------------------------------------------------------
// fp32 -> bf16 row-major convert
// ---------------------------------------------------------------------------
__global__ __launch_bounds__(256) void conv_bf16(
    const float* __restrict__ src, unsigned short* __restrict__ dst)
{
    int i = (blockIdx.x * 256 + threadIdx.x) * 4;
    float4 v = *(const float4*)(src + i);
    ushort4 o;
    o.x = f2b(v.x); o.y = f2b(v.y); o.z = f2b(v.z); o.w = f2b(v.w);
    *(ushort4*)(dst + i) = o;
}

// ---------------------------------------------------------------------------
// fp32 (R x C) -> bf16 transposed (C x R). blockIdx.z = matrix index.
// ---------------------------------------------------------------------------
__global__ __launch_bounds__(256) void transpose_conv(
    const float* __restrict__ src, unsigned short* __restrict__ dst, int R, int C)
{
    __shared__ float tile[32][33];
    const size_t moff = (size_t)blockIdx.z * R * C;
    src += moff; dst += moff;
    const int c0 = blockIdx.x * 32, r0 = blockIdx.y * 32;
    const int tx = threadIdx.x & 31, ty = threadIdx.x >> 5;   // 32 x 8
    #pragma unroll
    for (int i = 0; i < 32; i += 8)
        tile[ty + i][tx] = src[(size_t)(r0 + ty + i) * C + c0 + tx];
    __syncthreads();
    #pragma unroll
    for (int i = 0; i < 32; i += 8)
        dst[(size_t)(c0 + ty + i) * R + r0 + tx] = f2b(tile[tx][ty + i]);
}

// ---------------------------------------------------------------------------
// bf16 MFMA GEMM core: 128x128 tile, BK=32, 16x16x32 MFMA, 4x4 acc per wave.
// ---------------------------------------------------------------------------
__device__ __forceinline__ void mfma_gemm_128(
    const unsigned short* __restrict__ A, int lda,
    const unsigned short* __restrict__ Bt, int ldb, int K,
    unsigned short* As, unsigned short* Bs, f32x4 acc[4][4])
{
    const int tid = threadIdx.x;
    const int wave = tid >> 6, lane = tid & 63;
    const int r4 = lane >> 2, c4 = (lane & 3) * 8;
    const int lrow = lane & 15, lquad = lane >> 4;
    const int wm = (wave >> 1) * 64, wn = (wave & 1) * 64;
    for (int k0 = 0; k0 < K; k0 += 32) {
        #pragma unroll
        for (int i = 0; i < 2; ++i) {
            int ar = wave * 32 + i * 16;
            gl2lds16(A  + (size_t)(ar + r4) * lda + k0 + c4, As + ar * 32);
            gl2lds16(Bt + (size_t)(ar + r4) * ldb + k0 + c4, Bs + ar * 32);
        }
        __syncthreads();
        bf16x8 af[4], bfr[4];
        #pragma unroll
        for (int i = 0; i < 4; ++i)
            af[i] = *(const bf16x8*)(As + (wm + i * 16 + lrow) * 32 + lquad * 8);
        #pragma unroll
        for (int j = 0; j < 4; ++j)
            bfr[j] = *(const bf16x8*)(Bs + (wn + j * 16 + lrow) * 32 + lquad * 8);
        #pragma unroll
        for (int i = 0; i < 4; ++i)
            #pragma unroll
            for (int j = 0; j < 4; ++j)
                acc[i][j] = __builtin_amdgcn_mfma_f32_16x16x32_bf16(af[i], bfr[j], acc[i][j], 0, 0, 0);
        __syncthreads();
    }
}

// ---------------------------------------------------------------------------
// QKV projection: xb (8192x1024 bf16) @ Wtb[panel] (128x1024 bf16 = W^T)
// Outputs bf16: Qbb/Kbb/Vbb (BH, S, 128) row-major; Vtb (BH, 8, 128dv, 512s).
// ---------------------------------------------------------------------------
__global__ __launch_bounds__(256) void gemm_qkv_mfma(
    const unsigned short* __restrict__ xb, const unsigned short* __restrict__ Wtb,
    unsigned short* __restrict__ Qbb, unsigned short* __restrict__ Kbb,
    unsigned short* __restrict__ Vbb, unsigned short* __restrict__ Vtb)
{
    __shared__ unsigned short As[128 * 32];
    __shared__ unsigned short Bs[128 * 32];
    const int m0 = blockIdx.x * 128;
    const int panel = blockIdx.y;
    const int which = panel >> 3, h = panel & 7;
    f32x4 acc[4][4] = {};
    mfma_gemm_128(xb + (size_t)m0 * 1024, 1024,
                  Wtb + (size_t)panel * 128 * 1024, 1024, 1024, As, Bs, acc);
    const int tid = threadIdx.x, wave = tid >> 6, lane = tid & 63;
    const int lrow = lane & 15, lquad = lane >> 4;
    const int wm = (wave >> 1) * 64, wn = (wave & 1) * 64;
    #pragma unroll
    for (int i = 0; i < 4; ++i)
        #pragma unroll
        for (int r = 0; r < 4; ++r) {
            int m = m0 + wm + i * 16 + lquad * 4 + r;
            int bb = m >> 12, s = m & 4095;
            int bh = bb * 8 + h;
            size_t rowbase = ((size_t)bh * 4096 + s) * 128;
            #pragma unroll
            for (int j = 0; j < 4; ++j) {
                int col = wn + j * 16 + lrow;
                unsigned short v = f2b(acc[i][j][r]);
                if (which == 0) Kbb[rowbase + col] = v;
                else if (which == 1) {
                    Vbb[rowbase + col] = v;
                    Vtb[(((size_t)bh * 8 + (s >> 9)) * 128 + col) * 512 + (s & 511)] = v;
                } else Qbb[rowbase + col] = v;
            }
        }
}

// ---------------------------------------------------------------------------
// Output projection: Attb (8192x1024 bf16) @ Woutb (1024x1024 bf16 = Wout^T)
// ---------------------------------------------------------------------------
__global__ __launch_bounds__(256) void gemm_out_mfma(
    const unsigned short* __restrict__ A, const unsigned short* __restrict__ Bt,
    float* __restrict__ C)
{
    __shared__ unsigned short As[128 * 32];
    __shared__ unsigned short Bs[128 * 32];
    const int m0 = blockIdx.x * 128, n0 = blockIdx.y * 128;
    f32x4 acc[4][4] = {};
    mfma_gemm_128(A + (size_t)m0 * 1024, 1024,
                  Bt + (size_t)n0 * 1024, 1024, 1024, As, Bs, acc);
    const int tid = threadIdx.x, wave = tid >> 6, lane = tid & 63;
    const int lrow = lane & 15, lquad = lane >> 4;
    const int wm = (wave >> 1) * 64, wn = (wave & 1) * 64;
    #pragma unroll
    for (int i = 0; i < 4; ++i)
        #pragma unroll
        for (int r = 0; r < 4; ++r) {
            int m = m0 + wm + i * 16 + lquad * 4 + r;
            #pragma unroll
            for (int j = 0; j < 4; ++j)
                C[(size_t)m * 1024 + n0 + wn + j * 16 + lrow] = acc[i][j][r];
        }
}

// ---------------------------------------------------------------------------
// MFMA flash attention over one (bh,seg,qtile of 64 rows). 4 waves x 16 rows.
// QK^T and PV via 16x16x32 bf16 MFMA; P round-trips LDS (C-layout -> A-layout).
// Writes (1-gate)*att_dot into Att (fp32).
// ---------------------------------------------------------------------------
__global__ __launch_bounds__(256) void attn_mfma(
    const unsigned short* __restrict__ Qbb, const unsigned short* __restrict__ Kbb,
    const unsigned short* __restrict__ Vtb, const float* __restrict__ betas,
    float* __restrict__ Att)
{
    __shared__ unsigned short Pl[4][16][72];   // per-wave P tile, padded stride
    const int tid = threadIdx.x, wave = tid >> 6, lane = tid & 63;
    const int n = lane & 15, quad = lane >> 4;
    const int bh = blockIdx.x >> 3, seg = blockIdx.x & 7, qt = blockIdx.y;
    const int b = bh >> 3, h = bh & 7;
    const float scale = 0.08838834764831845f;

    const unsigned short* Qp = Qbb + ((size_t)bh * 4096 + seg * 512 + qt * 64 + wave * 16) * 128;
    const unsigned short* Kp = Kbb + ((size_t)bh * 4096 + seg * 512) * 128;
    const unsigned short* Vp = Vtb + ((size_t)bh * 8 + seg) * 128 * 512;

    bf16x8 aQ[4];
    #pragma unroll
    for (int kc = 0; kc < 4; ++kc)
        aQ[kc] = *(const bf16x8*)(Qp + n * 128 + kc * 32 + quad * 8);

    f32x4 O[8] = {};
    float m_i[4], l_i[4];
    #pragma unroll
    for (int r = 0; r < 4; ++r) { m_i[r] = -1e30f; l_i[r] = 0.f; }

    for (int jt = 0; jt <= qt; ++jt) {
        f32x4 Sf[4] = {};
        #pragma unroll
        for (int kc = 0; kc < 4; ++kc) {
            bf16x8 bK[4];
            #pragma unroll
            for (int ns = 0; ns < 4; ++ns)
                bK[ns] = *(const bf16x8*)(Kp + (size_t)(jt * 64 + ns * 16 + n) * 128 + kc * 32 + quad * 8);
            #pragma unroll
            for (int ns = 0; ns < 4; ++ns)
                Sf[ns] = __builtin_amdgcn_mfma_f32_16x16x32_bf16(aQ[kc], bK[ns], Sf[ns], 0, 0, 0);
        }
        // online softmax; C-layout: col = n, row = quad*4+reg (local in 16-row wave tile)
        #pragma unroll
        for (int reg = 0; reg < 4; ++reg) {
            int grow = qt * 64 + wave * 16 + quad * 4 + reg;
            float sv[4];
            #pragma unroll
            for (int ns = 0; ns < 4; ++ns) {
                int gcol = jt * 64 + ns * 16 + n;
                sv[ns] = (gcol <= grow) ? Sf[ns][reg] * scale : -1e30f;
            }
            float mx = fmaxf(fmaxf(sv[0], sv[1]), fmaxf(sv[2], sv[3]));
            mx = fmaxf(mx, __shfl_xor(mx, 1));
            mx = fmaxf(mx, __shfl_xor(mx, 2));
            mx = fmaxf(mx, __shfl_xor(mx, 4));
            mx = fmaxf(mx, __shfl_xor(mx, 8));
            float mn = fmaxf(m_i[reg], mx);
            float alpha = __expf(m_i[reg] - mn);
            m_i[reg] = mn;
            float rs = 0.f;
            #pragma unroll
            for (int ns = 0; ns < 4; ++ns) {
                float p = __expf(sv[ns] - mn);
                rs += p;
                Pl[wave][quad * 4 + reg][ns * 16 + n] = f2b(p);
            }
            rs += __shfl_xor(rs, 1);
            rs += __shfl_xor(rs, 2);
            rs += __shfl_xor(rs, 4);
            rs += __shfl_xor(rs, 8);
            l_i[reg] = l_i[reg] * alpha + rs;
            #pragma unroll
            for (int dvs = 0; dvs < 8; ++dvs) O[dvs][reg] *= alpha;
        }
        __syncthreads();       // P visible (also cross-lane within wave)
        bf16x8 aP0 = *(const bf16x8*)&Pl[wave][n][quad * 8];
        bf16x8 aP1 = *(const bf16x8*)&Pl[wave][n][32 + quad * 8];
        #pragma unroll
        for (int dvs = 0; dvs < 8; ++dvs) {
            bf16x8 bV0 = *(const bf16x8*)(Vp + (size_t)(dvs * 16 + n) * 512 + jt * 64 + quad * 8);
            bf16x8 bV1 = *(const bf16x8*)(Vp + (size_t)(dvs * 16 + n) * 512 + jt * 64 + 32 + quad * 8);
            O[dvs] = __builtin_amdgcn_mfma_f32_16x16x32_bf16(aP0, bV0, O[dvs], 0, 0, 0);
            O[dvs] = __builtin_amdgcn_mfma_f32_16x16x32_bf16(aP1, bV1, O[dvs], 0, 0, 0);
        }
        __syncthreads();       // P region reused next jt
    }
    float inv[4];
    #pragma unroll
    for (int r = 0; r < 4; ++r) inv[r] = 1.f / l_i[r];
    #pragma unroll
    for (int dvs = 0; dvs < 8; ++dvs) {
        int dv = dvs * 16 + n;
        float g = 1.f - sigmoidf(betas[h * 128 + dv]);
        #pragma unroll
        for (int reg = 0; reg < 4; ++reg) {
            int s = seg * 512 + qt * 64 + wave * 16 + quad * 4 + reg;
            Att[((size_t)b * 4096 + s) * 1024 + h * 128 + dv] = g * O[dvs][reg] * inv[reg];
        }
    }
}

// ---------------------------------------------------------------------------
// Fused delta-rule scan: ONE launch. wg = (bh, dv-chunk of 8 cols) -> exclusive
// ownership of mem[:,chunk] and a private z replica; both resident in LDS
// across all 8 segments. 512 threads: waves 0-3 attmix, waves 4-7 delta,
// all waves accumulate the rank-512 mem update in registers.
// ---------------------------------------------------------------------------
__global__ __launch_bounds__(512) void scan_fused(
    const unsigned short* __restrict__ Qbb, const unsigned short* __restrict__ Kbb,
    const unsigned short* __restrict__ Vbb, const float* __restrict__ betas,
    float* __restrict__ Att)
{
    __shared__ float memc[128][8];     // mem[:, chunk]
    __shared__ float zloc[128];        // private z replica
    __shared__ float sigk[64][129];    // sigma_k tile (for update phase)
    __shared__ float dloc[64][8];      // delta tile
    const int t = threadIdx.x;
    const int bh = blockIdx.x >> 4, chunk = blockIdx.x & 15;
    const int b = bh >> 3, h = bh & 7;
    const int dv0 = chunk * 8;
    const int wv = t >> 6, lane = t & 63;
    const int rr = lane >> 2, ks = lane & 3;
    const int edk = t >> 2, edv = (t & 3) * 2;

    if (t < 128) zloc[t] = 1.f / 128.f;
    { int e = t * 2; memc[e >> 3][e & 7] = 0.f; memc[(e + 1) >> 3][(e + 1) & 7] = 0.f; }
    float g[8];
    #pragma unroll
    for (int c = 0; c < 8; ++c) g[c] = sigmoidf(betas[h * 128 + dv0 + c]);
    float upd0 = 0.f, upd1 = 0.f, zacc = 0.f;
    __syncthreads();

    for (int seg = 0; seg < 8; ++seg) {
        for (int tile = 0; tile < 8; ++tile) {
            const size_t rowg0 = (size_t)bh * 4096 + seg * 512 + tile * 64;
            __syncthreads();           // prev E done with sigk/dloc
            // ---- A: stage sigma_k tile (all 512 threads, 16 elems each)
            {
                int f = t * 16;
                int row = f >> 7, kc = f & 127;
                const unsigned short* p = Kbb + (rowg0 + row) * 128 + kc;
                #pragma unroll
                for (int u = 0; u < 2; ++u) {
                    ushort4 a = *(const ushort4*)(p + u * 8);
                    ushort4 bq = *(const ushort4*)(p + u * 8 + 4);
                    sigk[row][kc + u * 8 + 0] = elu1(b2f(a.x));
                    sigk[row][kc + u * 8 + 1] = elu1(b2f(a.y));
                    sigk[row][kc + u * 8 + 2] = elu1(b2f(a.z));
                    sigk[row][kc + u * 8 + 3] = elu1(b2f(a.w));
                    sigk[row][kc + u * 8 + 4] = elu1(b2f(bq.x));
                    sigk[row][kc + u * 8 + 5] = elu1(b2f(bq.y));
                    sigk[row][kc + u * 8 + 6] = elu1(b2f(bq.z));
                    sigk[row][kc + u * 8 + 7] = elu1(b2f(bq.w));
                }
            }
            // ---- B (waves 0-3): attmix rows / D (waves 4-7): delta rows
            {
                const int r = (wv & 3) * 16 + rr;
                const unsigned short* sp = ((wv < 4) ? Qbb : Kbb) + (rowg0 + r) * 128 + ks * 32;
                float sq[32];
                #pragma unroll
                for (int u = 0; u < 4; ++u) {
                    ushort4 a = *(const ushort4*)(sp + u * 8);
                    ushort4 c = *(const ushort4*)(sp + u * 8 + 4);
                    sq[u * 8 + 0] = elu1(b2f(a.x)); sq[u * 8 + 1] = elu1(b2f(a.y));
                    sq[u * 8 + 2] = elu1(b2f(a.z)); sq[u * 8 + 3] = elu1(b2f(a.w));
                    sq[u * 8 + 4] = elu1(b2f(c.x)); sq[u * 8 + 5] = elu1(b2f(c.y));
                    sq[u * 8 + 6] = elu1(b2f(c.z)); sq[u * 8 + 7] = elu1(b2f(c.w));
                }
                float md[8] = {};
                float zd = 0.f;
                #pragma unroll
                for (int kk = 0; kk < 32; ++kk) {
                    int k = ks * 32 + kk;
                    float s = sq[kk];
                    float4 m0 = *(const float4*)&memc[k][0];
                    float4 m1 = *(const float4*)&memc[k][4];
                    zd += s * zloc[k];
                    md[0] += s * m0.x; md[1] += s * m0.y;
                    md[2] += s * m0.z; md[3] += s * m0.w;
                    md[4] += s * m1.x; md[5] += s * m1.y;
                    md[6] += s * m1.z; md[7] += s * m1.w;
                }
                #pragma unroll
                for (int j = 0; j < 8; ++j) {
                    md[j] += __shfl_xor(md[j], 1);
                    md[j] += __shfl_xor(md[j], 2);
                }
                zd += __shfl_xor(zd, 1);
                zd += __shfl_xor(zd, 2);
                if (ks == 0) {
                    float invz = 1.f / zd;
                    if (wv < 4) {  // attmix: Att += gate * (sq@mem)/(sq@z)
                        size_t a = ((size_t)b * 4096 + seg * 512 + tile * 64 + r) * 1024 + h * 128 + dv0;
                        float4 o0 = *(float4*)&Att[a];
                        float4 o1 = *(float4*)&Att[a + 4];
                        o0.x += g[0] * md[0] * invz; o0.y += g[1] * md[1] * invz;
                        o0.z += g[2] * md[2] * invz; o0.w += g[3] * md[3] * invz;
                        o1.x += g[4] * md[4] * invz; o1.y += g[5] * md[5] * invz;
                        o1.z += g[6] * md[6] * invz; o1.w += g[7] * md[7] * invz;
                        *(float4*)&Att[a] = o0; *(float4*)&Att[a + 4] = o1;
                    } else {       // delta = v - (sk@mem)/(sk@z)
                        const unsigned short* vp = Vbb + (rowg0 + r) * 128 + dv0;
                        ushort4 v0 = *(const ushort4*)vp;
                        ushort4 v1 = *(const ushort4*)(vp + 4);
                        dloc[r][0] = b2f(v0.x) - md[0] * invz;
                        dloc[r][1] = b2f(v0.y) - md[1] * invz;
                        dloc[r][2] = b2f(v0.z) - md[2] * invz;
                        dloc[r][3] = b2f(v0.w) - md[3] * invz;
                        dloc[r][4] = b2f(v1.x) - md[4] * invz;
                        dloc[r][5] = b2f(v1.y) - md[5] * invz;
                        dloc[r][6] = b2f(v1.z) - md[6] * invz;
                        dloc[r][7] = b2f(v1.w) - md[7] * invz;
                    }
                }
            }
            __syncthreads();           // sigk + dloc ready
            // ---- E: upd[dk][dv] += sum_s sigk[s][dk] * dloc[s][dv]
            #pragma unroll 16
            for (int s = 0; s < 64; ++s) {
                float sk = sigk[s][edk];
                float2 d = *(const float2*)&dloc[s][edv];
                upd0 += sk * d.x;
                upd1 += sk * d.y;
                if ((t & 3) == 0) zacc += sk;
            }
        }
        // apply segment update (exclusive ownership; all B/D reads done)
        memc[edk][edv]     += upd0;
        memc[edk][edv + 1] += upd1;
        if ((t & 3) == 0) zloc[edk] += zacc;
        upd0 = upd1 = zacc = 0.f;
        __syncthreads();
    }
}

extern "C" void kernel_launch(void* const* d_in, const int* in_sizes, int n_in,
                              void* d_out, int out_size, void* d_ws, size_t ws_size,
                              hipStream_t stream) {
    const float* x     = (const float*)d_in[0];
    const float* Wk    = (const float*)d_in[1];
    const float* Wv    = (const float*)d_in[2];
    const float* Wq    = (const float*)d_in[3];
    const float* Wout  = (const float*)d_in[4];
    const float* betas = (const float*)d_in[5];
    float* out = (float*)d_out;
    float* ws = (float*)d_ws;

    // workspace layout (~98 MB)
    float* Att = ws;                                        // 8388608 f32 (B,S,H*DV)
    unsigned short* Qbb = (unsigned short*)(ws + 8388608);  // 8388608 bf16 (BH,S,128)
    unsigned short* Kbb = Qbb + 8388608;
    unsigned short* Vbb = Kbb + 8388608;
    unsigned short* Vtb = Vbb + 8388608;                    // (BH,8,128dv,512s)
    // staging aliases (dead regions at time of use):
    unsigned short* xb    = (unsigned short*)Att;           // consumed before attn writes Att
    unsigned short* Wtb   = xb + 8388608;                   // (3,8,128,1024) W^T bf16
    unsigned short* Attb  = Qbb;                            // Qbb dead after scan
    unsigned short* Woutb = Kbb;                            // Kbb dead after scan

    conv_bf16<<<8192, 256, 0, stream>>>(x, xb);
    transpose_conv<<<dim3(4, 32, 8), 256, 0, stream>>>(Wk, Wtb,               1024, 128);
    transpose_conv<<<dim3(4, 32, 8), 256, 0, stream>>>(Wv, Wtb +  8 * 131072, 1024, 128);
    transpose_conv<<<dim3(4, 32, 8), 256, 0, stream>>>(Wq, Wtb + 16 * 131072, 1024, 128);
    gemm_qkv_mfma<<<dim3(64, 24), 256, 0, stream>>>(xb, Wtb, Qbb, Kbb, Vbb, Vtb);
    attn_mfma<<<dim3(128, 8), 256, 0, stream>>>(Qbb, Kbb, Vtb, betas, Att);
    scan_fused<<<256, 512, 0, stream>>>(Qbb, Kbb, Vbb, betas, Att);
    conv_bf16<<<8192, 256, 0, stream>>>(Att, Attb);
    transpose_conv<<<dim3(32, 32, 1), 256, 0, stream>>>(Wout, Woutb, 1024, 1024);
    gemm_out_mfma<<<dim3(64, 8), 256, 0, stream>>>(Attb, Woutb, out);
}

// Round 4
// 488.053 us; speedup vs baseline: 3.6243x; 1.5199x over previous
//
#include <hip/hip_runtime.h>

// Problem constants
#define B_  2
#define S_  4096
#define D_  1024
#define H_  8
#define DK_ 128
#define DV_ 128
#define SEG_ 512
#define NSEG_ 8
#define BH_ 16
#define M_ 8192          // B*S

typedef __attribute__((ext_vector_type(8))) short bf16x8;
typedef __attribute__((ext_vector_type(4))) float f32x4;

__device__ __forceinline__ float elu1(float x) { return x > 0.f ? x + 1.f : __expf(x); }
__device__ __forceinline__ float sigmoidf(float x) { return 1.f / (1.f + __expf(-x)); }

__device__ __forceinline__ unsigned short f2b(float f) {  // RNE fp32->bf16
    union { float f; unsigned int u; } x; x.f = f;
    unsigned int r = x.u + 0x7fffu + ((x.u >> 16) & 1u);
    return (unsigned short)(r >> 16);
}
__device__ __forceinline__ float b2f(unsigned short u) {
    union { unsigned int u; float f; } x; x.u = ((unsigned int)u) << 16; return x.f;
}

__device__ __forceinline__ void gl2lds16(const void* g, void* l) {
    __builtin_amdgcn_global_load_lds(
        (const __attribute__((address_space(1))) void*)g,
        (__attribute__((address_space(3))) void*)l, 16, 0, 0);
}

// ---------------------------------------------------------------------------
// fp32 -> bf16 row-major convert
// ---------------------------------------------------------------------------
__global__ __launch_bounds__(256) void conv_bf16(
    const float* __restrict__ src, unsigned short* __restrict__ dst)
{
    int i = (blockIdx.x * 256 + threadIdx.x) * 4;
    float4 v = *(const float4*)(src + i);
    ushort4 o;
    o.x = f2b(v.x); o.y = f2b(v.y); o.z = f2b(v.z); o.w = f2b(v.w);
    *(ushort4*)(dst + i) = o;
}

// ---------------------------------------------------------------------------
// fp32 (R x C) -> bf16 transposed (C x R). blockIdx.z = matrix index.
// ---------------------------------------------------------------------------
__global__ __launch_bounds__(256) void transpose_conv(
    const float* __restrict__ src, unsigned short* __restrict__ dst, int R, int C)
{
    __shared__ float tile[32][33];
    const size_t moff = (size_t)blockIdx.z * R * C;
    src += moff; dst += moff;
    const int c0 = blockIdx.x * 32, r0 = blockIdx.y * 32;
    const int tx = threadIdx.x & 31, ty = threadIdx.x >> 5;   // 32 x 8
    #pragma unroll
    for (int i = 0; i < 32; i += 8)
        tile[ty + i][tx] = src[(size_t)(r0 + ty + i) * C + c0 + tx];
    __syncthreads();
    #pragma unroll
    for (int i = 0; i < 32; i += 8)
        dst[(size_t)(c0 + ty + i) * R + r0 + tx] = f2b(tile[tx][ty + i]);
}

// ---------------------------------------------------------------------------
// sigma_k^T prep: SkT[bh][dk][s] = f2b(elu1(Kbb[bh][s][dk]))
// ---------------------------------------------------------------------------
__global__ __launch_bounds__(256) void sigma_kT(
    const unsigned short* __restrict__ Kbb, unsigned short* __restrict__ SkT)
{
    __shared__ float tile[32][33];
    const int bh = blockIdx.z;
    const int s0 = blockIdx.x * 32, dk0 = blockIdx.y * 32;
    const int tx = threadIdx.x & 31, ty = threadIdx.x >> 5;   // 32 x 8
    #pragma unroll
    for (int i = 0; i < 32; i += 8)
        tile[ty + i][tx] = elu1(b2f(Kbb[((size_t)bh * 4096 + s0 + ty + i) * 128 + dk0 + tx]));
    __syncthreads();
    #pragma unroll
    for (int i = 0; i < 32; i += 8)
        SkT[((size_t)bh * 128 + dk0 + ty + i) * 4096 + s0 + tx] = f2b(tile[tx][ty + i]);
}

// ---------------------------------------------------------------------------
// bf16 MFMA GEMM core: 128x128 tile, BK=32, 16x16x32 MFMA, 4x4 acc per wave.
// ---------------------------------------------------------------------------
__device__ __forceinline__ void mfma_gemm_128(
    const unsigned short* __restrict__ A, int lda,
    const unsigned short* __restrict__ Bt, int ldb, int K,
    unsigned short* As, unsigned short* Bs, f32x4 acc[4][4])
{
    const int tid = threadIdx.x;
    const int wave = tid >> 6, lane = tid & 63;
    const int r4 = lane >> 2, c4 = (lane & 3) * 8;
    const int lrow = lane & 15, lquad = lane >> 4;
    const int wm = (wave >> 1) * 64, wn = (wave & 1) * 64;
    for (int k0 = 0; k0 < K; k0 += 32) {
        #pragma unroll
        for (int i = 0; i < 2; ++i) {
            int ar = wave * 32 + i * 16;
            gl2lds16(A  + (size_t)(ar + r4) * lda + k0 + c4, As + ar * 32);
            gl2lds16(Bt + (size_t)(ar + r4) * ldb + k0 + c4, Bs + ar * 32);
        }
        __syncthreads();
        bf16x8 af[4], bfr[4];
        #pragma unroll
        for (int i = 0; i < 4; ++i)
            af[i] = *(const bf16x8*)(As + (wm + i * 16 + lrow) * 32 + lquad * 8);
        #pragma unroll
        for (int j = 0; j < 4; ++j)
            bfr[j] = *(const bf16x8*)(Bs + (wn + j * 16 + lrow) * 32 + lquad * 8);
        #pragma unroll
        for (int i = 0; i < 4; ++i)
            #pragma unroll
            for (int j = 0; j < 4; ++j)
                acc[i][j] = __builtin_amdgcn_mfma_f32_16x16x32_bf16(af[i], bfr[j], acc[i][j], 0, 0, 0);
        __syncthreads();
    }
}

// ---------------------------------------------------------------------------
// QKV projection: xb (8192x1024 bf16) @ Wtb[panel] (128x1024 bf16 = W^T)
// Outputs bf16: Qbb/Kbb/Vbb (BH, S, 128) row-major; Vtb (BH, 8, 128dv, 512s).
// ---------------------------------------------------------------------------
__global__ __launch_bounds__(256) void gemm_qkv_mfma(
    const unsigned short* __restrict__ xb, const unsigned short* __restrict__ Wtb,
    unsigned short* __restrict__ Qbb, unsigned short* __restrict__ Kbb,
    unsigned short* __restrict__ Vbb, unsigned short* __restrict__ Vtb)
{
    __shared__ unsigned short As[128 * 32];
    __shared__ unsigned short Bs[128 * 32];
    const int m0 = blockIdx.x * 128;
    const int panel = blockIdx.y;
    const int which = panel >> 3, h = panel & 7;
    f32x4 acc[4][4] = {};
    mfma_gemm_128(xb + (size_t)m0 * 1024, 1024,
                  Wtb + (size_t)panel * 128 * 1024, 1024, 1024, As, Bs, acc);
    const int tid = threadIdx.x, wave = tid >> 6, lane = tid & 63;
    const int lrow = lane & 15, lquad = lane >> 4;
    const int wm = (wave >> 1) * 64, wn = (wave & 1) * 64;
    #pragma unroll
    for (int i = 0; i < 4; ++i)
        #pragma unroll
        for (int r = 0; r < 4; ++r) {
            int m = m0 + wm + i * 16 + lquad * 4 + r;
            int bb = m >> 12, s = m & 4095;
            int bh = bb * 8 + h;
            size_t rowbase = ((size_t)bh * 4096 + s) * 128;
            #pragma unroll
            for (int j = 0; j < 4; ++j) {
                int col = wn + j * 16 + lrow;
                unsigned short v = f2b(acc[i][j][r]);
                if (which == 0) Kbb[rowbase + col] = v;
                else if (which == 1) {
                    Vbb[rowbase + col] = v;
                    Vtb[(((size_t)bh * 8 + (s >> 9)) * 128 + col) * 512 + (s & 511)] = v;
                } else Qbb[rowbase + col] = v;
            }
        }
}

// ---------------------------------------------------------------------------
// Output projection: Attb (8192x1024 bf16) @ Woutb (1024x1024 bf16 = Wout^T)
// ---------------------------------------------------------------------------
__global__ __launch_bounds__(256) void gemm_out_mfma(
    const unsigned short* __restrict__ A, const unsigned short* __restrict__ Bt,
    float* __restrict__ C)
{
    __shared__ unsigned short As[128 * 32];
    __shared__ unsigned short Bs[128 * 32];
    const int m0 = blockIdx.x * 128, n0 = blockIdx.y * 128;
    f32x4 acc[4][4] = {};
    mfma_gemm_128(A + (size_t)m0 * 1024, 1024,
                  Bt + (size_t)n0 * 1024, 1024, 1024, As, Bs, acc);
    const int tid = threadIdx.x, wave = tid >> 6, lane = tid & 63;
    const int lrow = lane & 15, lquad = lane >> 4;
    const int wm = (wave >> 1) * 64, wn = (wave & 1) * 64;
    #pragma unroll
    for (int i = 0; i < 4; ++i)
        #pragma unroll
        for (int r = 0; r < 4; ++r) {
            int m = m0 + wm + i * 16 + lquad * 4 + r;
            #pragma unroll
            for (int j = 0; j < 4; ++j)
                C[(size_t)m * 1024 + n0 + wn + j * 16 + lrow] = acc[i][j][r];
        }
}

// ---------------------------------------------------------------------------
// MFMA flash attention over one (bh,seg,qtile of 64 rows). 4 waves x 16 rows.
// Writes (1-gate)*att_dot into Att (fp32).
// ---------------------------------------------------------------------------
__global__ __launch_bounds__(256) void attn_mfma(
    const unsigned short* __restrict__ Qbb, const unsigned short* __restrict__ Kbb,
    const unsigned short* __restrict__ Vtb, const float* __restrict__ betas,
    float* __restrict__ Att)
{
    __shared__ unsigned short Pl[4][16][72];   // per-wave P tile, padded stride
    const int tid = threadIdx.x, wave = tid >> 6, lane = tid & 63;
    const int n = lane & 15, quad = lane >> 4;
    const int bh = blockIdx.x >> 3, seg = blockIdx.x & 7, qt = blockIdx.y;
    const int b = bh >> 3, h = bh & 7;
    const float scale = 0.08838834764831845f;

    const unsigned short* Qp = Qbb + ((size_t)bh * 4096 + seg * 512 + qt * 64 + wave * 16) * 128;
    const unsigned short* Kp = Kbb + ((size_t)bh * 4096 + seg * 512) * 128;
    const unsigned short* Vp = Vtb + ((size_t)bh * 8 + seg) * 128 * 512;

    bf16x8 aQ[4];
    #pragma unroll
    for (int kc = 0; kc < 4; ++kc)
        aQ[kc] = *(const bf16x8*)(Qp + n * 128 + kc * 32 + quad * 8);

    f32x4 O[8] = {};
    float m_i[4], l_i[4];
    #pragma unroll
    for (int r = 0; r < 4; ++r) { m_i[r] = -1e30f; l_i[r] = 0.f; }

    for (int jt = 0; jt <= qt; ++jt) {
        f32x4 Sf[4] = {};
        #pragma unroll
        for (int kc = 0; kc < 4; ++kc) {
            bf16x8 bK[4];
            #pragma unroll
            for (int ns = 0; ns < 4; ++ns)
                bK[ns] = *(const bf16x8*)(Kp + (size_t)(jt * 64 + ns * 16 + n) * 128 + kc * 32 + quad * 8);
            #pragma unroll
            for (int ns = 0; ns < 4; ++ns)
                Sf[ns] = __builtin_amdgcn_mfma_f32_16x16x32_bf16(aQ[kc], bK[ns], Sf[ns], 0, 0, 0);
        }
        #pragma unroll
        for (int reg = 0; reg < 4; ++reg) {
            int grow = qt * 64 + wave * 16 + quad * 4 + reg;
            float sv[4];
            #pragma unroll
            for (int ns = 0; ns < 4; ++ns) {
                int gcol = jt * 64 + ns * 16 + n;
                sv[ns] = (gcol <= grow) ? Sf[ns][reg] * scale : -1e30f;
            }
            float mx = fmaxf(fmaxf(sv[0], sv[1]), fmaxf(sv[2], sv[3]));
            mx = fmaxf(mx, __shfl_xor(mx, 1));
            mx = fmaxf(mx, __shfl_xor(mx, 2));
            mx = fmaxf(mx, __shfl_xor(mx, 4));
            mx = fmaxf(mx, __shfl_xor(mx, 8));
            float mn = fmaxf(m_i[reg], mx);
            float alpha = __expf(m_i[reg] - mn);
            m_i[reg] = mn;
            float rs = 0.f;
            #pragma unroll
            for (int ns = 0; ns < 4; ++ns) {
                float p = __expf(sv[ns] - mn);
                rs += p;
                Pl[wave][quad * 4 + reg][ns * 16 + n] = f2b(p);
            }
            rs += __shfl_xor(rs, 1);
            rs += __shfl_xor(rs, 2);
            rs += __shfl_xor(rs, 4);
            rs += __shfl_xor(rs, 8);
            l_i[reg] = l_i[reg] * alpha + rs;
            #pragma unroll
            for (int dvs = 0; dvs < 8; ++dvs) O[dvs][reg] *= alpha;
        }
        __syncthreads();
        bf16x8 aP0 = *(const bf16x8*)&Pl[wave][n][quad * 8];
        bf16x8 aP1 = *(const bf16x8*)&Pl[wave][n][32 + quad * 8];
        #pragma unroll
        for (int dvs = 0; dvs < 8; ++dvs) {
            bf16x8 bV0 = *(const bf16x8*)(Vp + (size_t)(dvs * 16 + n) * 512 + jt * 64 + quad * 8);
            bf16x8 bV1 = *(const bf16x8*)(Vp + (size_t)(dvs * 16 + n) * 512 + jt * 64 + 32 + quad * 8);
            O[dvs] = __builtin_amdgcn_mfma_f32_16x16x32_bf16(aP0, bV0, O[dvs], 0, 0, 0);
            O[dvs] = __builtin_amdgcn_mfma_f32_16x16x32_bf16(aP1, bV1, O[dvs], 0, 0, 0);
        }
        __syncthreads();
    }
    float inv[4];
    #pragma unroll
    for (int r = 0; r < 4; ++r) inv[r] = 1.f / l_i[r];
    #pragma unroll
    for (int dvs = 0; dvs < 8; ++dvs) {
        int dv = dvs * 16 + n;
        float g = 1.f - sigmoidf(betas[h * 128 + dv]);
        #pragma unroll
        for (int reg = 0; reg < 4; ++reg) {
            int s = seg * 512 + qt * 64 + wave * 16 + quad * 4 + reg;
            Att[((size_t)b * 4096 + s) * 1024 + h * 128 + dv] = g * O[dvs][reg] * inv[reg];
        }
    }
}

// ---------------------------------------------------------------------------
// MFMA delta-rule scan. wg = (bh, dv-chunk of 32): 64 wgs x 512 thr (8 waves).
// memT (fp32 master + bf16 shadow) resident in LDS across all 8 segments.
// Per segment: phase1 = sigma_q@mem (attmix->Att RMW) and sigma_k@mem
// (delta -> DlT in LDS), A-frags built on the fly from Q/K (elu fused, den
// via in-register dot with z); phase2 = mem += sigma_k^T @ delta via MFMA
// with A-frags from pre-transposed SkT, z colsum via ones-column B-frag.
// ---------------------------------------------------------------------------
__global__ __launch_bounds__(512) void scan_mfma(
    const unsigned short* __restrict__ Qbb, const unsigned short* __restrict__ Kbb,
    const unsigned short* __restrict__ Vbb, const unsigned short* __restrict__ SkT,
    const float* __restrict__ betas, float* __restrict__ Att)
{
    __shared__ float memT_f32[32][132];         // [dvloc][dk] master
    __shared__ unsigned short memT_bf[32][136]; // bf16 shadow for b-frags
    __shared__ unsigned short DlT[32][520];     // delta^T [dvloc][s_loc]
    __shared__ float zloc[128];
    const int t = threadIdx.x;
    const int wv = t >> 6, lane = t & 63;
    const int n16 = lane & 15, quad = lane >> 4;
    const int bh = blockIdx.x >> 2, chunk = blockIdx.x & 3;
    const int b = bh >> 3, h = bh & 7;
    const int dv0 = chunk * 32;

    const float g0 = sigmoidf(betas[h * 128 + dv0 + n16]);
    const float g1 = sigmoidf(betas[h * 128 + dv0 + 16 + n16]);

    for (int i = t; i < 32 * 132; i += 512) ((float*)memT_f32)[i] = 0.f;
    if (t < 128) zloc[t] = 1.f / 128.f;
    __syncthreads();

    for (int seg = 0; seg < 8; ++seg) {
        // ---- rebuild bf16 shadow of memT; reload z into regs
        {
            int row = t >> 4, col = (t & 15) * 8;
            float4 a = *(float4*)&memT_f32[row][col];
            float4 c = *(float4*)&memT_f32[row][col + 4];
            bf16x8 o;
            o[0] = (short)f2b(a.x); o[1] = (short)f2b(a.y);
            o[2] = (short)f2b(a.z); o[3] = (short)f2b(a.w);
            o[4] = (short)f2b(c.x); o[5] = (short)f2b(c.y);
            o[6] = (short)f2b(c.z); o[7] = (short)f2b(c.w);
            *(bf16x8*)&memT_bf[row][col] = o;
        }
        float zq[32];
        #pragma unroll
        for (int kf = 0; kf < 4; ++kf) {
            float4 z0 = *(float4*)&zloc[kf * 32 + quad * 8];
            float4 z1 = *(float4*)&zloc[kf * 32 + quad * 8 + 4];
            zq[kf * 8 + 0] = z0.x; zq[kf * 8 + 1] = z0.y;
            zq[kf * 8 + 2] = z0.z; zq[kf * 8 + 3] = z0.w;
            zq[kf * 8 + 4] = z1.x; zq[kf * 8 + 5] = z1.y;
            zq[kf * 8 + 6] = z1.z; zq[kf * 8 + 7] = z1.w;
        }
        __syncthreads();

        // ---- phase 1: attmix (u<4) and delta (u>=4), 1 mtile of 16 rows each
        for (int u = 0; u < 8; ++u) {
            const int isq = (u < 4);
            const int mtile = wv * 4 + (u & 3);
            const unsigned short* src = (isq ? Qbb : Kbb)
                + ((size_t)bh * 4096 + seg * 512 + mtile * 16 + n16) * 128;
            f32x4 acc0 = {}, acc1 = {};
            float den = 0.f;
            bf16x8 afr[4];
            #pragma unroll
            for (int kf = 0; kf < 4; ++kf) {
                bf16x8 raw = *(const bf16x8*)(src + kf * 32 + quad * 8);
                float v[8];
                #pragma unroll
                for (int j = 0; j < 8; ++j) {
                    v[j] = elu1(b2f((unsigned short)raw[j]));
                    den += v[j] * zq[kf * 8 + j];
                }
                bf16x8 a;
                #pragma unroll
                for (int j = 0; j < 8; ++j) a[j] = (short)f2b(v[j]);
                afr[kf] = a;
            }
            den += __shfl_xor(den, 16);
            den += __shfl_xor(den, 32);
            #pragma unroll
            for (int kf = 0; kf < 4; ++kf) {
                bf16x8 b0 = *(const bf16x8*)&memT_bf[n16][kf * 32 + quad * 8];
                bf16x8 b1 = *(const bf16x8*)&memT_bf[16 + n16][kf * 32 + quad * 8];
                acc0 = __builtin_amdgcn_mfma_f32_16x16x32_bf16(afr[kf], b0, acc0, 0, 0, 0);
                acc1 = __builtin_amdgcn_mfma_f32_16x16x32_bf16(afr[kf], b1, acc1, 0, 0, 0);
            }
            float ir[4];
            #pragma unroll
            for (int r = 0; r < 4; ++r) ir[r] = 1.f / __shfl(den, quad * 4 + r);
            const int sl = mtile * 16 + quad * 4;    // segment-local row base
            if (isq) {
                size_t a0 = ((size_t)b * 4096 + seg * 512 + sl) * 1024 + h * 128 + dv0 + n16;
                #pragma unroll
                for (int r = 0; r < 4; ++r) {
                    Att[a0 + (size_t)r * 1024]      += g0 * acc0[r] * ir[r];
                    Att[a0 + (size_t)r * 1024 + 16] += g1 * acc1[r] * ir[r];
                }
            } else {
                const unsigned short* vp = Vbb
                    + ((size_t)bh * 4096 + seg * 512 + sl) * 128 + dv0 + n16;
                #pragma unroll
                for (int r = 0; r < 4; ++r) {
                    float d0 = b2f(vp[(size_t)r * 128])      - acc0[r] * ir[r];
                    float d1 = b2f(vp[(size_t)r * 128 + 16]) - acc1[r] * ir[r];
                    DlT[n16][sl + r]      = f2b(d0);
                    DlT[16 + n16][sl + r] = f2b(d1);
                }
            }
        }
        __syncthreads();

        // ---- phase 2: mem += sigma_k^T @ delta (wave wv owns dk tile wv)
        {
            const unsigned short* at = SkT
                + ((size_t)bh * 128 + wv * 16 + n16) * 4096 + seg * 512;
            f32x4 u0 = {}, u1 = {}, uz = {};
            bf16x8 onesf;
            #pragma unroll
            for (int j = 0; j < 8; ++j) onesf[j] = (n16 == 0) ? (short)0x3F80 : (short)0;
            #pragma unroll 4
            for (int kf = 0; kf < 16; ++kf) {
                bf16x8 a = *(const bf16x8*)(at + kf * 32 + quad * 8);
                bf16x8 b0 = *(const bf16x8*)&DlT[n16][kf * 32 + quad * 8];
                bf16x8 b1 = *(const bf16x8*)&DlT[16 + n16][kf * 32 + quad * 8];
                u0 = __builtin_amdgcn_mfma_f32_16x16x32_bf16(a, b0, u0, 0, 0, 0);
                u1 = __builtin_amdgcn_mfma_f32_16x16x32_bf16(a, b1, u1, 0, 0, 0);
                uz = __builtin_amdgcn_mfma_f32_16x16x32_bf16(a, onesf, uz, 0, 0, 0);
            }
            // C-layout: col = dvloc (n16), row = dk_rel (quad*4+r)
            float4* p0 = (float4*)&memT_f32[n16][wv * 16 + quad * 4];
            float4* p1 = (float4*)&memT_f32[16 + n16][wv * 16 + quad * 4];
            float4 m0 = *p0, m1 = *p1;
            m0.x += u0[0]; m0.y += u0[1]; m0.z += u0[2]; m0.w += u0[3];
            m1.x += u1[0]; m1.y += u1[1]; m1.z += u1[2]; m1.w += u1[3];
            *p0 = m0; *p1 = m1;
            if (n16 == 0) {
                #pragma unroll
                for (int r = 0; r < 4; ++r) zloc[wv * 16 + quad * 4 + r] += uz[r];
            }
        }
        __syncthreads();
    }
}

extern "C" void kernel_launch(void* const* d_in, const int* in_sizes, int n_in,
                              void* d_out, int out_size, void* d_ws, size_t ws_size,
                              hipStream_t stream) {
    const float* x     = (const float*)d_in[0];
    const float* Wk    = (const float*)d_in[1];
    const float* Wv    = (const float*)d_in[2];
    const float* Wq    = (const float*)d_in[3];
    const float* Wout  = (const float*)d_in[4];
    const float* betas = (const float*)d_in[5];
    float* out = (float*)d_out;
    float* ws = (float*)d_ws;

    // workspace (~118 MB)
    float* Att = ws;                                        // 8388608 f32 (B,S,H*DV)
    unsigned short* Qbb = (unsigned short*)(ws + 8388608);  // 8388608 us (BH,S,128)
    unsigned short* Kbb = Qbb + 8388608;
    unsigned short* Vbb = Kbb + 8388608;
    unsigned short* Vtb = Vbb + 8388608;                    // (BH,8,128dv,512s)
    unsigned short* SkT = Vtb + 8388608;                    // (BH,128dk,4096s)
    // staging aliases (dead regions at time of use):
    unsigned short* xb    = (unsigned short*)Att;           // consumed before attn writes Att
    unsigned short* Wtb   = xb + 8388608;                   // (3,8,128,1024) W^T bf16
    unsigned short* Attb  = Qbb;                            // Qbb dead after scan
    unsigned short* Woutb = Kbb;                            // Kbb dead after scan

    conv_bf16<<<8192, 256, 0, stream>>>(x, xb);
    transpose_conv<<<dim3(4, 32, 8), 256, 0, stream>>>(Wk, Wtb,               1024, 128);
    transpose_conv<<<dim3(4, 32, 8), 256, 0, stream>>>(Wv, Wtb +  8 * 131072, 1024, 128);
    transpose_conv<<<dim3(4, 32, 8), 256, 0, stream>>>(Wq, Wtb + 16 * 131072, 1024, 128);
    gemm_qkv_mfma<<<dim3(64, 24), 256, 0, stream>>>(xb, Wtb, Qbb, Kbb, Vbb, Vtb);
    sigma_kT<<<dim3(128, 4, 16), 256, 0, stream>>>(Kbb, SkT);
    attn_mfma<<<dim3(128, 8), 256, 0, stream>>>(Qbb, Kbb, Vtb, betas, Att);
    scan_mfma<<<64, 512, 0, stream>>>(Qbb, Kbb, Vbb, SkT, betas, Att);
    conv_bf16<<<8192, 256, 0, stream>>>(Att, Attb);
    transpose_conv<<<dim3(32, 32, 1), 256, 0, stream>>>(Wout, Woutb, 1024, 1024);
    gemm_out_mfma<<<dim3(64, 8), 256, 0, stream>>>(Attb, Woutb, out);
}